// Round 3
// baseline (1611.699 us; speedup 1.0000x reference)
//
#include <hip/hip_runtime.h>
#include <hip/hip_bf16.h>

#define NN 50000
#define NE 800000
#define ET (NE + NN)          // 850000 edges incl. self-loops
#define NG 64
#define IND 128
#define HD 64
#define NH 4
#define D1 256                // NH*HD
#define BN_EPS 1e-5f
#define SLOPE 0.2f

// ---------------- CSR build (by dst) ----------------
__global__ void k_count(const int* __restrict__ ei, int* __restrict__ cnt){
  int e = blockIdx.x*256 + threadIdx.x;
  if (e >= ET) return;
  int d = (e < NE) ? ei[NE + e] : (e - NE);
  atomicAdd(&cnt[d], 1);
}

__global__ __launch_bounds__(1024) void k_scan1(const int* __restrict__ cnt,
                                                int* __restrict__ ro, int* __restrict__ part){
  __shared__ int s[1024];
  int i = blockIdx.x*1024 + threadIdx.x;
  int v = (i < NN) ? cnt[i] : 0;
  s[threadIdx.x] = v;
  __syncthreads();
  for (int off = 1; off < 1024; off <<= 1){
    int t = (threadIdx.x >= off) ? s[threadIdx.x - off] : 0;
    __syncthreads();
    s[threadIdx.x] += t;
    __syncthreads();
  }
  if (i < NN) ro[i] = s[threadIdx.x] - v;        // exclusive within block
  if (threadIdx.x == 1023) part[blockIdx.x] = s[1023];
}

__global__ __launch_bounds__(64) void k_scan2(int* __restrict__ part, int nb){
  __shared__ int s[64];
  int v = (threadIdx.x < nb) ? part[threadIdx.x] : 0;
  s[threadIdx.x] = v;
  __syncthreads();
  for (int off = 1; off < 64; off <<= 1){
    int t = (threadIdx.x >= off) ? s[threadIdx.x - off] : 0;
    __syncthreads();
    s[threadIdx.x] += t;
    __syncthreads();
  }
  if (threadIdx.x < nb) part[threadIdx.x] = s[threadIdx.x] - v;  // exclusive
}

__global__ __launch_bounds__(1024) void k_scan3(const int* __restrict__ part, int* __restrict__ ro){
  int i = blockIdx.x*1024 + threadIdx.x;
  if (i < NN) ro[i] += part[blockIdx.x];
  if (i == 0) ro[NN] = ET;
}

__global__ void k_scatter(const int* __restrict__ ei, const int* __restrict__ ro,
                          int* __restrict__ cur, int* __restrict__ ssrc, int* __restrict__ sdst){
  int e = blockIdx.x*256 + threadIdx.x;
  if (e >= ET) return;
  int s, d;
  if (e < NE){ s = ei[e]; d = ei[NE + e]; } else { s = e - NE; d = s; }
  int pos = ro[d] + atomicAdd(&cur[d], 1);
  ssrc[pos] = s;
  sdst[pos] = d;
}

// ---------------- Layer 1: xl = x@Wl+bl, xr = x@Wr+br  (IND=128 -> D1=256) ----------------
__global__ __launch_bounds__(256) void k_gemm1(const float* __restrict__ x,
      const float* __restrict__ Wl, const float* __restrict__ bl,
      const float* __restrict__ Wr, const float* __restrict__ br,
      float* __restrict__ xl, float* __restrict__ xr){
  __shared__ float sx[4][IND];
  int n0 = blockIdx.x*4;
  for (int t = threadIdx.x; t < 4*IND; t += 256){
    int ni = t >> 7, k = t & (IND-1);
    int n = n0 + ni;
    sx[ni][k] = (n < NN) ? x[(size_t)n*IND + k] : 0.f;
  }
  __syncthreads();
  int c = threadIdx.x;
  float blv = bl[c], brv = br[c];
  float al[4], ar[4];
  #pragma unroll
  for (int i = 0; i < 4; i++){ al[i] = blv; ar[i] = brv; }
  for (int k = 0; k < IND; k++){
    float wl = Wl[k*D1 + c];
    float wr = Wr[k*D1 + c];
    #pragma unroll
    for (int i = 0; i < 4; i++){
      al[i] += sx[i][k]*wl;
      ar[i] += sx[i][k]*wr;
    }
  }
  #pragma unroll
  for (int i = 0; i < 4; i++){
    int n = n0 + i;
    if (n < NN){ xl[(size_t)n*D1 + c] = al[i]; xr[(size_t)n*D1 + c] = ar[i]; }
  }
}

// wave per edge: logits[e][h] = sum_c att[h][c] * leaky(xl[src][h*64+c] + xr[dst][h*64+c])
__global__ __launch_bounds__(256) void k_logits1(const int* __restrict__ ssrc, const int* __restrict__ sdst,
      const float* __restrict__ xl, const float* __restrict__ xr,
      const float* __restrict__ att, float* __restrict__ lg){
  int widx = threadIdx.x >> 6, lane = threadIdx.x & 63;
  int e = blockIdx.x*4 + widx;
  if (e >= ET) return;
  int s = ssrc[e], d = sdst[e];
  const float* rl = &xl[(size_t)s*D1];
  const float* rr = &xr[(size_t)d*D1];
  float acc[NH];
  #pragma unroll
  for (int h = 0; h < NH; h++){
    float v = rl[h*HD + lane] + rr[h*HD + lane];
    v = (v > 0.f) ? v : SLOPE*v;
    acc[h] = v * att[h*HD + lane];
  }
  #pragma unroll
  for (int off = 32; off > 0; off >>= 1){
    #pragma unroll
    for (int h = 0; h < NH; h++) acc[h] += __shfl_xor(acc[h], off, 64);
  }
  if (lane == 0){
    float4 o = make_float4(acc[0], acc[1], acc[2], acc[3]);
    *reinterpret_cast<float4*>(&lg[(size_t)e*4]) = o;
  }
}

// wave per node: segment softmax + aggregate alpha*xl[src], +bias
__global__ __launch_bounds__(256) void k_agg1(const int* __restrict__ ro, const int* __restrict__ ssrc,
      const float* __restrict__ lg, const float* __restrict__ xl,
      const float* __restrict__ bias, float* __restrict__ out){
  int widx = threadIdx.x >> 6, lane = threadIdx.x & 63;
  int n = blockIdx.x*4 + widx;
  if (n >= NN) return;
  int b = ro[n], e = ro[n+1];
  float m0=-1e30f, m1=-1e30f, m2=-1e30f, m3=-1e30f;
  for (int i = b; i < e; i++){
    float4 v = *reinterpret_cast<const float4*>(&lg[(size_t)i*4]);
    m0 = fmaxf(m0, v.x); m1 = fmaxf(m1, v.y); m2 = fmaxf(m2, v.z); m3 = fmaxf(m3, v.w);
  }
  float d0=0.f, d1=0.f, d2=0.f, d3=0.f;
  for (int i = b; i < e; i++){
    float4 v = *reinterpret_cast<const float4*>(&lg[(size_t)i*4]);
    d0 += __expf(v.x - m0); d1 += __expf(v.y - m1);
    d2 += __expf(v.z - m2); d3 += __expf(v.w - m3);
  }
  float i0 = 1.f/d0, i1 = 1.f/d1, i2 = 1.f/d2, i3 = 1.f/d3;
  float a0=0.f, a1=0.f, a2=0.f, a3=0.f;
  for (int i = b; i < e; i++){
    float4 v = *reinterpret_cast<const float4*>(&lg[(size_t)i*4]);
    const float* row = &xl[(size_t)ssrc[i]*D1];
    float w0 = __expf(v.x - m0)*i0;
    float w1 = __expf(v.y - m1)*i1;
    float w2 = __expf(v.z - m2)*i2;
    float w3 = __expf(v.w - m3)*i3;
    a0 += w0*row[0*HD + lane];
    a1 += w1*row[1*HD + lane];
    a2 += w2*row[2*HD + lane];
    a3 += w3*row[3*HD + lane];
  }
  float* orow = &out[(size_t)n*D1];
  orow[0*HD + lane] = a0 + bias[0*HD + lane];
  orow[1*HD + lane] = a1 + bias[1*HD + lane];
  orow[2*HD + lane] = a2 + bias[2*HD + lane];
  orow[3*HD + lane] = a3 + bias[3*HD + lane];
}

// ---------------- BatchNorm ----------------
__global__ __launch_bounds__(256) void k_bnstats(const float* __restrict__ h, float* __restrict__ stats,
                                                 int ncols, int rpb){
  int nrl = 256/ncols;
  int c = threadIdx.x % ncols;
  int rl = threadIdx.x / ncols;
  int r0 = blockIdx.x*rpb + rl;
  int r1 = min(NN, (blockIdx.x+1)*rpb);
  float s = 0.f, s2 = 0.f;
  for (int r = r0; r < r1; r += nrl){
    float v = h[(size_t)r*ncols + c];
    s += v; s2 += v*v;
  }
  atomicAdd(&stats[c], s);
  atomicAdd(&stats[ncols + c], s2);
}

__global__ void k_bn1(float* __restrict__ h, const float* __restrict__ stats,
                      const float* __restrict__ gamma, const float* __restrict__ beta){
  const float invn = 1.f/NN;
  size_t total = (size_t)NN*D1;
  for (size_t i = (size_t)blockIdx.x*blockDim.x + threadIdx.x; i < total;
       i += (size_t)gridDim.x*blockDim.x){
    int c = (int)(i & (D1-1));
    float mu = stats[c]*invn;
    float var = stats[D1 + c]*invn - mu*mu;
    float g = gamma[c] * rsqrtf(var + BN_EPS);
    float v = (h[i] - mu)*g + beta[c];
    h[i] = (v > 0.f) ? v : (__expf(v) - 1.f);
  }
}

// ---------------- Layer 2 (heads=1) ----------------
__global__ __launch_bounds__(256) void k_gemm2(const float* __restrict__ h,
      const float* __restrict__ Wl, const float* __restrict__ bl,
      const float* __restrict__ Wr, const float* __restrict__ br,
      float* __restrict__ xl, float* __restrict__ xr){
  __shared__ float sh[4][D1];
  int n0 = blockIdx.x*4;
  for (int t = threadIdx.x; t < 4*D1; t += 256){
    int ni = t >> 8, k = t & (D1-1);
    int n = n0 + ni;
    sh[ni][k] = (n < NN) ? h[(size_t)n*D1 + k] : 0.f;
  }
  __syncthreads();
  int ni = threadIdx.x >> 6, c = threadIdx.x & 63;
  int n = n0 + ni;
  float al = bl[c], ar = br[c];
  for (int k = 0; k < D1; k++){
    float xv = sh[ni][k];
    al += xv*Wl[k*HD + c];
    ar += xv*Wr[k*HD + c];
  }
  if (n < NN){ xl[(size_t)n*HD + c] = al; xr[(size_t)n*HD + c] = ar; }
}

__global__ __launch_bounds__(256) void k_logits2(const int* __restrict__ ssrc, const int* __restrict__ sdst,
      const float* __restrict__ xl, const float* __restrict__ xr,
      const float* __restrict__ att, float* __restrict__ lg){
  int widx = threadIdx.x >> 6, lane = threadIdx.x & 63;
  int e = blockIdx.x*4 + widx;
  if (e >= ET) return;
  int s = ssrc[e], d = sdst[e];
  float v = xl[(size_t)s*HD + lane] + xr[(size_t)d*HD + lane];
  v = (v > 0.f) ? v : SLOPE*v;
  float a = v * att[lane];
  #pragma unroll
  for (int off = 32; off > 0; off >>= 1) a += __shfl_xor(a, off, 64);
  if (lane == 0) lg[e] = a;
}

__global__ __launch_bounds__(256) void k_agg2(const int* __restrict__ ro, const int* __restrict__ ssrc,
      const float* __restrict__ lg, const float* __restrict__ xl,
      const float* __restrict__ bias, float* __restrict__ out){
  int widx = threadIdx.x >> 6, lane = threadIdx.x & 63;
  int n = blockIdx.x*4 + widx;
  if (n >= NN) return;
  int b = ro[n], e = ro[n+1];
  float m = -1e30f;
  for (int i = b; i < e; i++) m = fmaxf(m, lg[i]);
  float den = 0.f;
  for (int i = b; i < e; i++) den += __expf(lg[i] - m);
  float inv = 1.f/den;
  float acc = 0.f;
  for (int i = b; i < e; i++){
    float w = __expf(lg[i] - m)*inv;
    acc += w * xl[(size_t)ssrc[i]*HD + lane];
  }
  out[(size_t)n*HD + lane] = acc + bias[lane];
}

// BN2 + ELU + pooled sums (batch ids) fused
__global__ void k_bn2pool(const float* __restrict__ h2, const float* __restrict__ stats,
      const float* __restrict__ gamma, const float* __restrict__ beta,
      const int* __restrict__ batch, float* __restrict__ pool, float* __restrict__ pcnt){
  int idx = blockIdx.x*256 + threadIdx.x;
  if (idx >= NN*HD) return;
  int n = idx >> 6, c = idx & 63;
  const float invn = 1.f/NN;
  float mu = stats[c]*invn;
  float var = stats[HD + c]*invn - mu*mu;
  float v = (h2[idx] - mu)*rsqrtf(var + BN_EPS)*gamma[c] + beta[c];
  v = (v > 0.f) ? v : (__expf(v) - 1.f);
  int g = batch[n];
  atomicAdd(&pool[g*HD + c], v);
  if (c == 0) atomicAdd(&pcnt[g], 1.f);
}

// final MLP: out[g] = elu(pooled@lw1+lb1) @ lw2 + lb2   (f32 output!)
__global__ __launch_bounds__(64) void k_mlp(const float* __restrict__ pool, const float* __restrict__ pcnt,
      const float* __restrict__ lw1, const float* __restrict__ lb1,
      const float* __restrict__ lw2, const float* __restrict__ lb2, float* __restrict__ out){
  __shared__ float p[HD];
  int g = blockIdx.x, c = threadIdx.x;
  float cnt = fmaxf(pcnt[g], 1.f);
  p[c] = pool[g*HD + c]/cnt;
  __syncthreads();
  float acc = lb1[c];
  for (int k = 0; k < HD; k++) acc += p[k]*lw1[k*HD + c];
  acc = (acc > 0.f) ? acc : (__expf(acc) - 1.f);
  float t = acc * lw2[c];
  #pragma unroll
  for (int off = 32; off > 0; off >>= 1) t += __shfl_xor(t, off, 64);
  if (c == 0) out[g] = t + lb2[0];
}

extern "C" void kernel_launch(void* const* d_in, const int* in_sizes, int n_in,
                              void* d_out, int out_size, void* d_ws, size_t ws_size,
                              hipStream_t stream){
  const float* x    = (const float*)d_in[0];
  const int*  ei    = (const int*) d_in[1];
  const int*  batch = (const int*) d_in[2];
  const float* W1l = (const float*)d_in[3];
  const float* b1l = (const float*)d_in[4];
  const float* W1r = (const float*)d_in[5];
  const float* b1r = (const float*)d_in[6];
  const float* att1= (const float*)d_in[7];
  const float* bias1=(const float*)d_in[8];
  const float* gamma1=(const float*)d_in[9];
  const float* beta1 =(const float*)d_in[10];
  const float* W2l = (const float*)d_in[11];
  const float* b2l = (const float*)d_in[12];
  const float* W2r = (const float*)d_in[13];
  const float* b2r = (const float*)d_in[14];
  const float* att2= (const float*)d_in[15];
  const float* bias2=(const float*)d_in[16];
  const float* gamma2=(const float*)d_in[17];
  const float* beta2 =(const float*)d_in[18];
  const float* lw1 = (const float*)d_in[19];
  const float* lb1 = (const float*)d_in[20];
  const float* lw2 = (const float*)d_in[21];
  const float* lb2 = (const float*)d_in[22];
  float* out = (float*)d_out;

  char* w = (char*)d_ws;
  size_t off = 0;
  auto take = [&](size_t bytes)->char*{
    char* p = w + off;
    off = (off + bytes + 255) & ~(size_t)255;
    return p;
  };
  int*   ro    = (int*)  take((NN+1)*sizeof(int));
  int*   cur   = (int*)  take((size_t)NN*sizeof(int));
  int*   ssrc  = (int*)  take((size_t)ET*sizeof(int));
  int*   sdst  = (int*)  take((size_t)ET*sizeof(int));
  int*   part  = (int*)  take(64*sizeof(int));
  float* stats1= (float*)take(2*D1*sizeof(float));
  float* stats2= (float*)take(2*HD*sizeof(float));
  float* pool  = (float*)take(NG*HD*sizeof(float));
  float* pcnt  = (float*)take(NG*sizeof(float));
  float* regA  = (float*)take((size_t)NN*D1*sizeof(float));  // xl1; later xl2/xr2/log2/h2
  float* regB  = (float*)take((size_t)NN*D1*sizeof(float));  // xr1; later h1
  float* log1  = (float*)take((size_t)ET*4*sizeof(float));

  float* xl1 = regA;
  float* xr1 = regB;
  float* h1  = regB;                               // overwrites xr1 (dead after k_logits1)
  float* xl2 = regA;                               // overwrites xl1 (dead after k_agg1)
  float* xr2 = regA + (size_t)NN*HD;
  float* log2= regA + (size_t)2*NN*HD;
  float* h2  = regA + (size_t)2*NN*HD + ET;

  // CSR build
  hipMemsetAsync(cur, 0, (size_t)NN*sizeof(int), stream);
  k_count<<<(ET+255)/256, 256, 0, stream>>>(ei, cur);
  int nsb = (NN + 1023)/1024;                       // 49 blocks
  k_scan1<<<nsb, 1024, 0, stream>>>(cur, ro, part);
  k_scan2<<<1, 64, 0, stream>>>(part, nsb);
  k_scan3<<<nsb, 1024, 0, stream>>>(part, ro);
  hipMemsetAsync(cur, 0, (size_t)NN*sizeof(int), stream);
  k_scatter<<<(ET+255)/256, 256, 0, stream>>>(ei, ro, cur, ssrc, sdst);

  // Layer 1
  k_gemm1<<<(NN+3)/4, 256, 0, stream>>>(x, W1l, b1l, W1r, b1r, xl1, xr1);
  k_logits1<<<(ET+3)/4, 256, 0, stream>>>(ssrc, sdst, xl1, xr1, att1, log1);
  k_agg1<<<(NN+3)/4, 256, 0, stream>>>(ro, ssrc, log1, xl1, bias1, h1);
  hipMemsetAsync(stats1, 0, 2*D1*sizeof(float), stream);
  k_bnstats<<<196, 256, 0, stream>>>(h1, stats1, D1, 256);
  k_bn1<<<2048, 256, 0, stream>>>(h1, stats1, gamma1, beta1);

  // Layer 2
  k_gemm2<<<(NN+3)/4, 256, 0, stream>>>(h1, W2l, b2l, W2r, b2r, xl2, xr2);
  k_logits2<<<(ET+3)/4, 256, 0, stream>>>(ssrc, sdst, xl2, xr2, att2, log2);
  k_agg2<<<(NN+3)/4, 256, 0, stream>>>(ro, ssrc, log2, xl2, bias2, h2);
  hipMemsetAsync(stats2, 0, 2*HD*sizeof(float), stream);
  k_bnstats<<<196, 256, 0, stream>>>(h2, stats2, HD, 256);

  // BN2 + ELU + pool, then MLP head
  hipMemsetAsync(pool, 0, NG*HD*sizeof(float), stream);
  hipMemsetAsync(pcnt, 0, NG*sizeof(float), stream);
  k_bn2pool<<<(NN*HD+255)/256, 256, 0, stream>>>(h2, stats2, gamma2, beta2, batch, pool, pcnt);
  k_mlp<<<NG, 64, 0, stream>>>(pool, pcnt, lw1, lb1, lw2, lb2, out);
}

// Round 4
// 1310.020 us; speedup vs baseline: 1.2303x; 1.2303x over previous
//
#include <hip/hip_runtime.h>
#include <hip/hip_bf16.h>

#define NN 50000
#define NE 800000
#define ET (NE + NN)          // 850000 edges incl. self-loops
#define NG 64
#define IND 128
#define HD 64
#define NH 4
#define D1 256                // NH*HD
#define BN_EPS 1e-5f
#define SLOPE 0.2f
#define PW_NODES 200          // nodes per wave in k_bn2pool

// ---------------- CSR build (by dst) ----------------
__global__ void k_count(const int* __restrict__ ei, int* __restrict__ cnt){
  int e = blockIdx.x*256 + threadIdx.x;
  if (e >= ET) return;
  int d = (e < NE) ? ei[NE + e] : (e - NE);
  atomicAdd(&cnt[d], 1);
}

__global__ __launch_bounds__(1024) void k_scan1(const int* __restrict__ cnt,
                                                int* __restrict__ ro, int* __restrict__ part){
  __shared__ int s[1024];
  int i = blockIdx.x*1024 + threadIdx.x;
  int v = (i < NN) ? cnt[i] : 0;
  s[threadIdx.x] = v;
  __syncthreads();
  for (int off = 1; off < 1024; off <<= 1){
    int t = (threadIdx.x >= off) ? s[threadIdx.x - off] : 0;
    __syncthreads();
    s[threadIdx.x] += t;
    __syncthreads();
  }
  if (i < NN) ro[i] = s[threadIdx.x] - v;        // exclusive within block
  if (threadIdx.x == 1023) part[blockIdx.x] = s[1023];
}

__global__ __launch_bounds__(64) void k_scan2(int* __restrict__ part, int nb){
  __shared__ int s[64];
  int v = (threadIdx.x < nb) ? part[threadIdx.x] : 0;
  s[threadIdx.x] = v;
  __syncthreads();
  for (int off = 1; off < 64; off <<= 1){
    int t = (threadIdx.x >= off) ? s[threadIdx.x - off] : 0;
    __syncthreads();
    s[threadIdx.x] += t;
    __syncthreads();
  }
  if (threadIdx.x < nb) part[threadIdx.x] = s[threadIdx.x] - v;  // exclusive
}

__global__ __launch_bounds__(1024) void k_scan3(const int* __restrict__ part, int* __restrict__ ro){
  int i = blockIdx.x*1024 + threadIdx.x;
  if (i < NN) ro[i] += part[blockIdx.x];
  if (i == 0) ro[NN] = ET;
}

__global__ void k_scatter(const int* __restrict__ ei, const int* __restrict__ ro,
                          int* __restrict__ cur, int* __restrict__ ssrc, int* __restrict__ sdst){
  int e = blockIdx.x*256 + threadIdx.x;
  if (e >= ET) return;
  int s, d;
  if (e < NE){ s = ei[e]; d = ei[NE + e]; } else { s = e - NE; d = s; }
  int pos = ro[d] + atomicAdd(&cur[d], 1);
  ssrc[pos] = s;
  sdst[pos] = d;
}

// ---------------- Layer 1: xl = x@Wl+bl, xr = x@Wr+br  (IND=128 -> D1=256) ----------------
__global__ __launch_bounds__(256) void k_gemm1(const float* __restrict__ x,
      const float* __restrict__ Wl, const float* __restrict__ bl,
      const float* __restrict__ Wr, const float* __restrict__ br,
      float* __restrict__ xl, float* __restrict__ xr){
  __shared__ float sx[4][IND];
  int n0 = blockIdx.x*4;
  for (int t = threadIdx.x; t < 4*IND; t += 256){
    int ni = t >> 7, k = t & (IND-1);
    int n = n0 + ni;
    sx[ni][k] = (n < NN) ? x[(size_t)n*IND + k] : 0.f;
  }
  __syncthreads();
  int c = threadIdx.x;
  float blv = bl[c], brv = br[c];
  float al[4], ar[4];
  #pragma unroll
  for (int i = 0; i < 4; i++){ al[i] = blv; ar[i] = brv; }
  for (int k = 0; k < IND; k++){
    float wl = Wl[k*D1 + c];
    float wr = Wr[k*D1 + c];
    #pragma unroll
    for (int i = 0; i < 4; i++){
      al[i] += sx[i][k]*wl;
      ar[i] += sx[i][k]*wr;
    }
  }
  #pragma unroll
  for (int i = 0; i < 4; i++){
    int n = n0 + i;
    if (n < NN){ xl[(size_t)n*D1 + c] = al[i]; xr[(size_t)n*D1 + c] = ar[i]; }
  }
}

// wave per edge: logits[e][h] = sum_c att[h][c] * leaky(xl[src][h*64+c] + xr[dst][h*64+c])
__global__ __launch_bounds__(256) void k_logits1(const int* __restrict__ ssrc, const int* __restrict__ sdst,
      const float* __restrict__ xl, const float* __restrict__ xr,
      const float* __restrict__ att, float* __restrict__ lg){
  int widx = threadIdx.x >> 6, lane = threadIdx.x & 63;
  int e = blockIdx.x*4 + widx;
  if (e >= ET) return;
  int s = ssrc[e], d = sdst[e];
  const float* rl = &xl[(size_t)s*D1];
  const float* rr = &xr[(size_t)d*D1];
  float acc[NH];
  #pragma unroll
  for (int h = 0; h < NH; h++){
    float v = rl[h*HD + lane] + rr[h*HD + lane];
    v = (v > 0.f) ? v : SLOPE*v;
    acc[h] = v * att[h*HD + lane];
  }
  #pragma unroll
  for (int off = 32; off > 0; off >>= 1){
    #pragma unroll
    for (int h = 0; h < NH; h++) acc[h] += __shfl_xor(acc[h], off, 64);
  }
  if (lane == 0){
    float4 o = make_float4(acc[0], acc[1], acc[2], acc[3]);
    *reinterpret_cast<float4*>(&lg[(size_t)e*4]) = o;
  }
}

// wave per node: segment softmax + aggregate alpha*xl[src], +bias
__global__ __launch_bounds__(256) void k_agg1(const int* __restrict__ ro, const int* __restrict__ ssrc,
      const float* __restrict__ lg, const float* __restrict__ xl,
      const float* __restrict__ bias, float* __restrict__ out){
  int widx = threadIdx.x >> 6, lane = threadIdx.x & 63;
  int n = blockIdx.x*4 + widx;
  if (n >= NN) return;
  int b = ro[n], e = ro[n+1];
  float m0=-1e30f, m1=-1e30f, m2=-1e30f, m3=-1e30f;
  for (int i = b; i < e; i++){
    float4 v = *reinterpret_cast<const float4*>(&lg[(size_t)i*4]);
    m0 = fmaxf(m0, v.x); m1 = fmaxf(m1, v.y); m2 = fmaxf(m2, v.z); m3 = fmaxf(m3, v.w);
  }
  float d0=0.f, d1=0.f, d2=0.f, d3=0.f;
  for (int i = b; i < e; i++){
    float4 v = *reinterpret_cast<const float4*>(&lg[(size_t)i*4]);
    d0 += __expf(v.x - m0); d1 += __expf(v.y - m1);
    d2 += __expf(v.z - m2); d3 += __expf(v.w - m3);
  }
  float i0 = 1.f/d0, i1 = 1.f/d1, i2 = 1.f/d2, i3 = 1.f/d3;
  float a0=0.f, a1=0.f, a2=0.f, a3=0.f;
  for (int i = b; i < e; i++){
    float4 v = *reinterpret_cast<const float4*>(&lg[(size_t)i*4]);
    const float* row = &xl[(size_t)ssrc[i]*D1];
    float w0 = __expf(v.x - m0)*i0;
    float w1 = __expf(v.y - m1)*i1;
    float w2 = __expf(v.z - m2)*i2;
    float w3 = __expf(v.w - m3)*i3;
    a0 += w0*row[0*HD + lane];
    a1 += w1*row[1*HD + lane];
    a2 += w2*row[2*HD + lane];
    a3 += w3*row[3*HD + lane];
  }
  float* orow = &out[(size_t)n*D1];
  orow[0*HD + lane] = a0 + bias[0*HD + lane];
  orow[1*HD + lane] = a1 + bias[1*HD + lane];
  orow[2*HD + lane] = a2 + bias[2*HD + lane];
  orow[3*HD + lane] = a3 + bias[3*HD + lane];
}

// ---------------- BatchNorm ----------------
__global__ __launch_bounds__(256) void k_bnstats(const float* __restrict__ h, float* __restrict__ stats,
                                                 int ncols, int rpb){
  int nrl = 256/ncols;
  int c = threadIdx.x % ncols;
  int rl = threadIdx.x / ncols;
  int r0 = blockIdx.x*rpb + rl;
  int r1 = min(NN, (blockIdx.x+1)*rpb);
  float s = 0.f, s2 = 0.f;
  for (int r = r0; r < r1; r += nrl){
    float v = h[(size_t)r*ncols + c];
    s += v; s2 += v*v;
  }
  atomicAdd(&stats[c], s);
  atomicAdd(&stats[ncols + c], s2);
}

__global__ void k_bn1(float* __restrict__ h, const float* __restrict__ stats,
                      const float* __restrict__ gamma, const float* __restrict__ beta){
  const float invn = 1.f/NN;
  size_t total = (size_t)NN*D1;
  for (size_t i = (size_t)blockIdx.x*blockDim.x + threadIdx.x; i < total;
       i += (size_t)gridDim.x*blockDim.x){
    int c = (int)(i & (D1-1));
    float mu = stats[c]*invn;
    float var = stats[D1 + c]*invn - mu*mu;
    float g = gamma[c] * rsqrtf(var + BN_EPS);
    float v = (h[i] - mu)*g + beta[c];
    h[i] = (v > 0.f) ? v : (__expf(v) - 1.f);
  }
}

// ---------------- Layer 2 (heads=1) ----------------
__global__ __launch_bounds__(256) void k_gemm2(const float* __restrict__ h,
      const float* __restrict__ Wl, const float* __restrict__ bl,
      const float* __restrict__ Wr, const float* __restrict__ br,
      float* __restrict__ xl, float* __restrict__ xr){
  __shared__ float sh[4][D1];
  int n0 = blockIdx.x*4;
  for (int t = threadIdx.x; t < 4*D1; t += 256){
    int ni = t >> 8, k = t & (D1-1);
    int n = n0 + ni;
    sh[ni][k] = (n < NN) ? h[(size_t)n*D1 + k] : 0.f;
  }
  __syncthreads();
  int ni = threadIdx.x >> 6, c = threadIdx.x & 63;
  int n = n0 + ni;
  float al = bl[c], ar = br[c];
  for (int k = 0; k < D1; k++){
    float xv = sh[ni][k];
    al += xv*Wl[k*HD + c];
    ar += xv*Wr[k*HD + c];
  }
  if (n < NN){ xl[(size_t)n*HD + c] = al; xr[(size_t)n*HD + c] = ar; }
}

__global__ __launch_bounds__(256) void k_logits2(const int* __restrict__ ssrc, const int* __restrict__ sdst,
      const float* __restrict__ xl, const float* __restrict__ xr,
      const float* __restrict__ att, float* __restrict__ lg){
  int widx = threadIdx.x >> 6, lane = threadIdx.x & 63;
  int e = blockIdx.x*4 + widx;
  if (e >= ET) return;
  int s = ssrc[e], d = sdst[e];
  float v = xl[(size_t)s*HD + lane] + xr[(size_t)d*HD + lane];
  v = (v > 0.f) ? v : SLOPE*v;
  float a = v * att[lane];
  #pragma unroll
  for (int off = 32; off > 0; off >>= 1) a += __shfl_xor(a, off, 64);
  if (lane == 0) lg[e] = a;
}

__global__ __launch_bounds__(256) void k_agg2(const int* __restrict__ ro, const int* __restrict__ ssrc,
      const float* __restrict__ lg, const float* __restrict__ xl,
      const float* __restrict__ bias, float* __restrict__ out){
  int widx = threadIdx.x >> 6, lane = threadIdx.x & 63;
  int n = blockIdx.x*4 + widx;
  if (n >= NN) return;
  int b = ro[n], e = ro[n+1];
  float m = -1e30f;
  for (int i = b; i < e; i++) m = fmaxf(m, lg[i]);
  float den = 0.f;
  for (int i = b; i < e; i++) den += __expf(lg[i] - m);
  float inv = 1.f/den;
  float acc = 0.f;
  for (int i = b; i < e; i++){
    float w = __expf(lg[i] - m)*inv;
    acc += w * xl[(size_t)ssrc[i]*HD + lane];
  }
  out[(size_t)n*HD + lane] = acc + bias[lane];
}

// BN2 + ELU + pooled sums, sorted-batch aware: one wave owns a contiguous
// node strip; per-group register accumulation, flush on group change.
__global__ __launch_bounds__(256) void k_bn2pool(const float* __restrict__ h2, const float* __restrict__ stats,
      const float* __restrict__ gamma, const float* __restrict__ beta,
      const int* __restrict__ batch, float* __restrict__ pool, float* __restrict__ pcnt){
  int wave = blockIdx.x*4 + (threadIdx.x >> 6);
  int lane = threadIdx.x & 63;
  int n0 = wave*PW_NODES;
  if (n0 >= NN) return;
  int n1 = min(NN, n0 + PW_NODES);
  const float invn = 1.f/NN;
  float mu = stats[lane]*invn;
  float var = stats[HD + lane]*invn - mu*mu;
  float sc = gamma[lane]*rsqrtf(var + BN_EPS);
  float sh = beta[lane] - mu*sc;
  int curg = batch[n0];
  float acc = 0.f, cnt = 0.f;
  for (int n = n0; n < n1; n++){
    int g = batch[n];
    if (g != curg){
      atomicAdd(&pool[curg*HD + lane], acc);
      if (lane == 0) atomicAdd(&pcnt[curg], cnt);
      acc = 0.f; cnt = 0.f; curg = g;
    }
    float v = h2[(size_t)n*HD + lane]*sc + sh;
    v = (v > 0.f) ? v : (__expf(v) - 1.f);
    acc += v; cnt += 1.f;
  }
  atomicAdd(&pool[curg*HD + lane], acc);
  if (lane == 0) atomicAdd(&pcnt[curg], cnt);
}

// final MLP: out[g] = elu(pooled@lw1+lb1) @ lw2 + lb2   (f32 output)
__global__ __launch_bounds__(64) void k_mlp(const float* __restrict__ pool, const float* __restrict__ pcnt,
      const float* __restrict__ lw1, const float* __restrict__ lb1,
      const float* __restrict__ lw2, const float* __restrict__ lb2, float* __restrict__ out){
  __shared__ float p[HD];
  int g = blockIdx.x, c = threadIdx.x;
  float cnt = fmaxf(pcnt[g], 1.f);
  p[c] = pool[g*HD + c]/cnt;
  __syncthreads();
  float acc = lb1[c];
  for (int k = 0; k < HD; k++) acc += p[k]*lw1[k*HD + c];
  acc = (acc > 0.f) ? acc : (__expf(acc) - 1.f);
  float t = acc * lw2[c];
  #pragma unroll
  for (int off = 32; off > 0; off >>= 1) t += __shfl_xor(t, off, 64);
  if (c == 0) out[g] = t + lb2[0];
}

extern "C" void kernel_launch(void* const* d_in, const int* in_sizes, int n_in,
                              void* d_out, int out_size, void* d_ws, size_t ws_size,
                              hipStream_t stream){
  const float* x    = (const float*)d_in[0];
  const int*  ei    = (const int*) d_in[1];
  const int*  batch = (const int*) d_in[2];
  const float* W1l = (const float*)d_in[3];
  const float* b1l = (const float*)d_in[4];
  const float* W1r = (const float*)d_in[5];
  const float* b1r = (const float*)d_in[6];
  const float* att1= (const float*)d_in[7];
  const float* bias1=(const float*)d_in[8];
  const float* gamma1=(const float*)d_in[9];
  const float* beta1 =(const float*)d_in[10];
  const float* W2l = (const float*)d_in[11];
  const float* b2l = (const float*)d_in[12];
  const float* W2r = (const float*)d_in[13];
  const float* b2r = (const float*)d_in[14];
  const float* att2= (const float*)d_in[15];
  const float* bias2=(const float*)d_in[16];
  const float* gamma2=(const float*)d_in[17];
  const float* beta2 =(const float*)d_in[18];
  const float* lw1 = (const float*)d_in[19];
  const float* lb1 = (const float*)d_in[20];
  const float* lw2 = (const float*)d_in[21];
  const float* lb2 = (const float*)d_in[22];
  float* out = (float*)d_out;

  char* w = (char*)d_ws;
  size_t off = 0;
  auto take = [&](size_t bytes)->char*{
    char* p = w + off;
    off = (off + bytes + 255) & ~(size_t)255;
    return p;
  };
  int*   ro    = (int*)  take((NN+1)*sizeof(int));
  int*   cur   = (int*)  take((size_t)NN*sizeof(int));
  int*   ssrc  = (int*)  take((size_t)ET*sizeof(int));
  int*   sdst  = (int*)  take((size_t)ET*sizeof(int));
  int*   part  = (int*)  take(64*sizeof(int));
  float* stats1= (float*)take(2*D1*sizeof(float));
  float* stats2= (float*)take(2*HD*sizeof(float));
  float* pool  = (float*)take(NG*HD*sizeof(float));
  float* pcnt  = (float*)take(NG*sizeof(float));
  float* regA  = (float*)take((size_t)NN*D1*sizeof(float));  // xl1; later xl2/xr2/log2/h2
  float* regB  = (float*)take((size_t)NN*D1*sizeof(float));  // xr1; later h1
  float* log1  = (float*)take((size_t)ET*4*sizeof(float));

  float* xl1 = regA;
  float* xr1 = regB;
  float* h1  = regB;                               // overwrites xr1 (dead after k_logits1)
  float* xl2 = regA;                               // overwrites xl1 (dead after k_agg1)
  float* xr2 = regA + (size_t)NN*HD;
  float* log2= regA + (size_t)2*NN*HD;
  float* h2  = regA + (size_t)2*NN*HD + ET;

  // CSR build
  hipMemsetAsync(cur, 0, (size_t)NN*sizeof(int), stream);
  k_count<<<(ET+255)/256, 256, 0, stream>>>(ei, cur);
  int nsb = (NN + 1023)/1024;                       // 49 blocks
  k_scan1<<<nsb, 1024, 0, stream>>>(cur, ro, part);
  k_scan2<<<1, 64, 0, stream>>>(part, nsb);
  k_scan3<<<nsb, 1024, 0, stream>>>(part, ro);
  hipMemsetAsync(cur, 0, (size_t)NN*sizeof(int), stream);
  k_scatter<<<(ET+255)/256, 256, 0, stream>>>(ei, ro, cur, ssrc, sdst);

  // Layer 1
  k_gemm1<<<(NN+3)/4, 256, 0, stream>>>(x, W1l, b1l, W1r, b1r, xl1, xr1);
  k_logits1<<<(ET+3)/4, 256, 0, stream>>>(ssrc, sdst, xl1, xr1, att1, log1);
  k_agg1<<<(NN+3)/4, 256, 0, stream>>>(ro, ssrc, log1, xl1, bias1, h1);
  hipMemsetAsync(stats1, 0, 2*D1*sizeof(float), stream);
  k_bnstats<<<196, 256, 0, stream>>>(h1, stats1, D1, 256);
  k_bn1<<<2048, 256, 0, stream>>>(h1, stats1, gamma1, beta1);

  // Layer 2
  k_gemm2<<<(NN+3)/4, 256, 0, stream>>>(h1, W2l, b2l, W2r, b2r, xl2, xr2);
  k_logits2<<<(ET+3)/4, 256, 0, stream>>>(ssrc, sdst, xl2, xr2, att2, log2);
  k_agg2<<<(NN+3)/4, 256, 0, stream>>>(ro, ssrc, log2, xl2, bias2, h2);
  hipMemsetAsync(stats2, 0, 2*HD*sizeof(float), stream);
  k_bnstats<<<196, 256, 0, stream>>>(h2, stats2, HD, 256);

  // BN2 + ELU + pool (sorted-batch strip reduction), then MLP head
  hipMemsetAsync(pool, 0, NG*HD*sizeof(float), stream);
  hipMemsetAsync(pcnt, 0, NG*sizeof(float), stream);
  {
    int waves = (NN + PW_NODES - 1)/PW_NODES;       // 250
    int blocks = (waves + 3)/4;                      // 63
    k_bn2pool<<<blocks, 256, 0, stream>>>(h2, stats2, gamma2, beta2, batch, pool, pcnt);
  }
  k_mlp<<<NG, 64, 0, stream>>>(pool, pcnt, lw1, lb1, lw2, lb2, out);
}

// Round 5
// 822.817 us; speedup vs baseline: 1.9588x; 1.5921x over previous
//
#include <hip/hip_runtime.h>
#include <hip/hip_bf16.h>

#define NN 50000
#define NE 800000
#define ET (NE + NN)          // 850000 edges incl. self-loops
#define NG 64
#define IND 128
#define HD 64
#define NH 4
#define D1 256                // NH*HD
#define BN_EPS 1e-5f
#define SLOPE 0.2f
#define PW_NODES 200          // nodes per wave in k_bn2pool

// ---------------- CSR build (by dst) ----------------
__global__ void k_count(const int* __restrict__ ei, int* __restrict__ cnt){
  int e = blockIdx.x*256 + threadIdx.x;
  if (e >= ET) return;
  int d = (e < NE) ? ei[NE + e] : (e - NE);
  atomicAdd(&cnt[d], 1);
}

__global__ __launch_bounds__(1024) void k_scan1(const int* __restrict__ cnt,
                                                int* __restrict__ ro, int* __restrict__ part){
  __shared__ int s[1024];
  int i = blockIdx.x*1024 + threadIdx.x;
  int v = (i < NN) ? cnt[i] : 0;
  s[threadIdx.x] = v;
  __syncthreads();
  for (int off = 1; off < 1024; off <<= 1){
    int t = (threadIdx.x >= off) ? s[threadIdx.x - off] : 0;
    __syncthreads();
    s[threadIdx.x] += t;
    __syncthreads();
  }
  if (i < NN) ro[i] = s[threadIdx.x] - v;        // exclusive within block
  if (threadIdx.x == 1023) part[blockIdx.x] = s[1023];
}

__global__ __launch_bounds__(64) void k_scan2(int* __restrict__ part, int nb){
  __shared__ int s[64];
  int v = (threadIdx.x < nb) ? part[threadIdx.x] : 0;
  s[threadIdx.x] = v;
  __syncthreads();
  for (int off = 1; off < 64; off <<= 1){
    int t = (threadIdx.x >= off) ? s[threadIdx.x - off] : 0;
    __syncthreads();
    s[threadIdx.x] += t;
    __syncthreads();
  }
  if (threadIdx.x < nb) part[threadIdx.x] = s[threadIdx.x] - v;  // exclusive
}

__global__ __launch_bounds__(1024) void k_scan3(const int* __restrict__ part, int* __restrict__ ro){
  int i = blockIdx.x*1024 + threadIdx.x;
  if (i < NN) ro[i] += part[blockIdx.x];
  if (i == 0) ro[NN] = ET;
}

__global__ void k_scatter(const int* __restrict__ ei, const int* __restrict__ ro,
                          int* __restrict__ cur, int* __restrict__ ssrc){
  int e = blockIdx.x*256 + threadIdx.x;
  if (e >= ET) return;
  int s, d;
  if (e < NE){ s = ei[e]; d = ei[NE + e]; } else { s = e - NE; d = s; }
  int pos = ro[d] + atomicAdd(&cur[d], 1);
  ssrc[pos] = s;
}

// ---------------- Layer 1: xl = x@Wl+bl, xr = x@Wr+br  (IND=128 -> D1=256) ----------------
__global__ __launch_bounds__(256) void k_gemm1(const float* __restrict__ x,
      const float* __restrict__ Wl, const float* __restrict__ bl,
      const float* __restrict__ Wr, const float* __restrict__ br,
      float* __restrict__ xl, float* __restrict__ xr){
  __shared__ float sx[4][IND];
  int n0 = blockIdx.x*4;
  for (int t = threadIdx.x; t < 4*IND; t += 256){
    int ni = t >> 7, k = t & (IND-1);
    int n = n0 + ni;
    sx[ni][k] = (n < NN) ? x[(size_t)n*IND + k] : 0.f;
  }
  __syncthreads();
  int c = threadIdx.x;
  float blv = bl[c], brv = br[c];
  float al[4], ar[4];
  #pragma unroll
  for (int i = 0; i < 4; i++){ al[i] = blv; ar[i] = brv; }
  for (int k = 0; k < IND; k++){
    float wl = Wl[k*D1 + c];
    float wr = Wr[k*D1 + c];
    #pragma unroll
    for (int i = 0; i < 4; i++){
      al[i] += sx[i][k]*wl;
      ar[i] += sx[i][k]*wr;
    }
  }
  #pragma unroll
  for (int i = 0; i < 4; i++){
    int n = n0 + i;
    if (n < NN){ xl[(size_t)n*D1 + c] = al[i]; xr[(size_t)n*D1 + c] = ar[i]; }
  }
}

// ---- Fused GATv2 layer 1: per-node online-softmax over incoming edges ----
// lane: h = lane>>4 (head), c4 = (lane&15)*4 (4 columns of that head)
__global__ __launch_bounds__(256) void k_gat1(const int* __restrict__ ro, const int* __restrict__ ssrc,
      const float* __restrict__ xl, const float* __restrict__ xr,
      const float* __restrict__ att, const float* __restrict__ bias,
      float* __restrict__ out){
  int widx = threadIdx.x >> 6, lane = threadIdx.x & 63;
  int n = blockIdx.x*4 + widx;
  if (n >= NN) return;
  int base = (lane >> 4)*HD + (lane & 15)*4;
  float4 xr4 = *reinterpret_cast<const float4*>(&xr[(size_t)n*D1 + base]);
  float4 at4 = *reinterpret_cast<const float4*>(&att[base]);
  float m = -1e30f, den = 0.f;
  float ax=0.f, ay=0.f, az=0.f, aw=0.f;
  int b = ro[n], e = ro[n+1];
  for (int i = b; i < e; i++){
    int s = ssrc[i];
    float4 v = *reinterpret_cast<const float4*>(&xl[(size_t)s*D1 + base]);
    float t0 = v.x + xr4.x; t0 = (t0 > 0.f) ? t0 : SLOPE*t0;
    float t1 = v.y + xr4.y; t1 = (t1 > 0.f) ? t1 : SLOPE*t1;
    float t2 = v.z + xr4.z; t2 = (t2 > 0.f) ? t2 : SLOPE*t2;
    float t3 = v.w + xr4.w; t3 = (t3 > 0.f) ? t3 : SLOPE*t3;
    float L = at4.x*t0 + at4.y*t1 + at4.z*t2 + at4.w*t3;
    L += __shfl_xor(L, 1); L += __shfl_xor(L, 2);
    L += __shfl_xor(L, 4); L += __shfl_xor(L, 8);
    float mn = fmaxf(m, L);
    float corr = __expf(m - mn);
    float p = __expf(L - mn);
    den = den*corr + p;
    ax = ax*corr + p*v.x;
    ay = ay*corr + p*v.y;
    az = az*corr + p*v.z;
    aw = aw*corr + p*v.w;
    m = mn;
  }
  float inv = 1.f/den;
  float4 b4 = *reinterpret_cast<const float4*>(&bias[base]);
  float4 o = make_float4(ax*inv + b4.x, ay*inv + b4.y, az*inv + b4.z, aw*inv + b4.w);
  *reinterpret_cast<float4*>(&out[(size_t)n*D1 + base]) = o;
}

// ---------------- BatchNorm ----------------
__global__ __launch_bounds__(256) void k_bnstats(const float* __restrict__ h, float* __restrict__ stats,
                                                 int ncols, int rpb){
  int nrl = 256/ncols;
  int c = threadIdx.x % ncols;
  int rl = threadIdx.x / ncols;
  int r0 = blockIdx.x*rpb + rl;
  int r1 = min(NN, (blockIdx.x+1)*rpb);
  float s = 0.f, s2 = 0.f;
  for (int r = r0; r < r1; r += nrl){
    float v = h[(size_t)r*ncols + c];
    s += v; s2 += v*v;
  }
  atomicAdd(&stats[c], s);
  atomicAdd(&stats[ncols + c], s2);
}

__global__ void k_bn1(float* __restrict__ h, const float* __restrict__ stats,
                      const float* __restrict__ gamma, const float* __restrict__ beta){
  const float invn = 1.f/NN;
  size_t total = (size_t)NN*D1;
  for (size_t i = (size_t)blockIdx.x*blockDim.x + threadIdx.x; i < total;
       i += (size_t)gridDim.x*blockDim.x){
    int c = (int)(i & (D1-1));
    float mu = stats[c]*invn;
    float var = stats[D1 + c]*invn - mu*mu;
    float g = gamma[c] * rsqrtf(var + BN_EPS);
    float v = (h[i] - mu)*g + beta[c];
    h[i] = (v > 0.f) ? v : (__expf(v) - 1.f);
  }
}

// ---------------- Layer 2 (heads=1) ----------------
__global__ __launch_bounds__(256) void k_gemm2(const float* __restrict__ h,
      const float* __restrict__ Wl, const float* __restrict__ bl,
      const float* __restrict__ Wr, const float* __restrict__ br,
      float* __restrict__ xl, float* __restrict__ xr){
  __shared__ float sh[4][D1];
  int n0 = blockIdx.x*4;
  for (int t = threadIdx.x; t < 4*D1; t += 256){
    int ni = t >> 8, k = t & (D1-1);
    int n = n0 + ni;
    sh[ni][k] = (n < NN) ? h[(size_t)n*D1 + k] : 0.f;
  }
  __syncthreads();
  int ni = threadIdx.x >> 6, c = threadIdx.x & 63;
  int n = n0 + ni;
  float al = bl[c], ar = br[c];
  for (int k = 0; k < D1; k++){
    float xv = sh[ni][k];
    al += xv*Wl[k*HD + c];
    ar += xv*Wr[k*HD + c];
  }
  if (n < NN){ xl[(size_t)n*HD + c] = al; xr[(size_t)n*HD + c] = ar; }
}

// ---- Fused GATv2 layer 2 (1 head): 4 lane-groups split the edge list,
// each runs online softmax on every 4th edge; merged via shfl at the end.
__global__ __launch_bounds__(256) void k_gat2(const int* __restrict__ ro, const int* __restrict__ ssrc,
      const float* __restrict__ xl, const float* __restrict__ xr,
      const float* __restrict__ att, const float* __restrict__ bias,
      float* __restrict__ out){
  int widx = threadIdx.x >> 6, lane = threadIdx.x & 63;
  int n = blockIdx.x*4 + widx;
  if (n >= NN) return;
  int g = lane >> 4, c4 = (lane & 15)*4;
  float4 xr4 = *reinterpret_cast<const float4*>(&xr[(size_t)n*HD + c4]);
  float4 at4 = *reinterpret_cast<const float4*>(&att[c4]);
  float m = -1e30f, den = 0.f;
  float ax=0.f, ay=0.f, az=0.f, aw=0.f;
  int b = ro[n], e = ro[n+1];
  for (int i = b + g; i < e; i += 4){
    int s = ssrc[i];
    float4 v = *reinterpret_cast<const float4*>(&xl[(size_t)s*HD + c4]);
    float t0 = v.x + xr4.x; t0 = (t0 > 0.f) ? t0 : SLOPE*t0;
    float t1 = v.y + xr4.y; t1 = (t1 > 0.f) ? t1 : SLOPE*t1;
    float t2 = v.z + xr4.z; t2 = (t2 > 0.f) ? t2 : SLOPE*t2;
    float t3 = v.w + xr4.w; t3 = (t3 > 0.f) ? t3 : SLOPE*t3;
    float L = at4.x*t0 + at4.y*t1 + at4.z*t2 + at4.w*t3;
    L += __shfl_xor(L, 1); L += __shfl_xor(L, 2);
    L += __shfl_xor(L, 4); L += __shfl_xor(L, 8);
    float mn = fmaxf(m, L);
    float corr = __expf(m - mn);
    float p = __expf(L - mn);
    den = den*corr + p;
    ax = ax*corr + p*v.x;
    ay = ay*corr + p*v.y;
    az = az*corr + p*v.z;
    aw = aw*corr + p*v.w;
    m = mn;
  }
  // merge the 4 per-group partials (lanes l and l^16 / l^32 share c4)
  #pragma unroll
  for (int off = 16; off <= 32; off <<= 1){
    float mo  = __shfl_xor(m, off);
    float dno = __shfl_xor(den, off);
    float bx  = __shfl_xor(ax, off);
    float by  = __shfl_xor(ay, off);
    float bz  = __shfl_xor(az, off);
    float bw  = __shfl_xor(aw, off);
    float mn = fmaxf(m, mo);
    float c1 = __expf(m - mn), c2 = __expf(mo - mn);
    den = den*c1 + dno*c2;
    ax = ax*c1 + bx*c2;
    ay = ay*c1 + by*c2;
    az = az*c1 + bz*c2;
    aw = aw*c1 + bw*c2;
    m = mn;
  }
  float inv = 1.f/den;
  float4 b4 = *reinterpret_cast<const float4*>(&bias[c4]);
  float4 o = make_float4(ax*inv + b4.x, ay*inv + b4.y, az*inv + b4.z, aw*inv + b4.w);
  *reinterpret_cast<float4*>(&out[(size_t)n*HD + c4]) = o;
}

// BN2 + ELU + pooled sums, sorted-batch aware: one wave owns a contiguous
// node strip; per-group register accumulation, flush on group change.
__global__ __launch_bounds__(256) void k_bn2pool(const float* __restrict__ h2, const float* __restrict__ stats,
      const float* __restrict__ gamma, const float* __restrict__ beta,
      const int* __restrict__ batch, float* __restrict__ pool, float* __restrict__ pcnt){
  int wave = blockIdx.x*4 + (threadIdx.x >> 6);
  int lane = threadIdx.x & 63;
  int n0 = wave*PW_NODES;
  if (n0 >= NN) return;
  int n1 = min(NN, n0 + PW_NODES);
  const float invn = 1.f/NN;
  float mu = stats[lane]*invn;
  float var = stats[HD + lane]*invn - mu*mu;
  float sc = gamma[lane]*rsqrtf(var + BN_EPS);
  float sh = beta[lane] - mu*sc;
  int curg = batch[n0];
  float acc = 0.f, cnt = 0.f;
  for (int n = n0; n < n1; n++){
    int g = batch[n];
    if (g != curg){
      atomicAdd(&pool[curg*HD + lane], acc);
      if (lane == 0) atomicAdd(&pcnt[curg], cnt);
      acc = 0.f; cnt = 0.f; curg = g;
    }
    float v = h2[(size_t)n*HD + lane]*sc + sh;
    v = (v > 0.f) ? v : (__expf(v) - 1.f);
    acc += v; cnt += 1.f;
  }
  atomicAdd(&pool[curg*HD + lane], acc);
  if (lane == 0) atomicAdd(&pcnt[curg], cnt);
}

// final MLP: out[g] = elu(pooled@lw1+lb1) @ lw2 + lb2   (f32 output)
__global__ __launch_bounds__(64) void k_mlp(const float* __restrict__ pool, const float* __restrict__ pcnt,
      const float* __restrict__ lw1, const float* __restrict__ lb1,
      const float* __restrict__ lw2, const float* __restrict__ lb2, float* __restrict__ out){
  __shared__ float p[HD];
  int g = blockIdx.x, c = threadIdx.x;
  float cnt = fmaxf(pcnt[g], 1.f);
  p[c] = pool[g*HD + c]/cnt;
  __syncthreads();
  float acc = lb1[c];
  for (int k = 0; k < HD; k++) acc += p[k]*lw1[k*HD + c];
  acc = (acc > 0.f) ? acc : (__expf(acc) - 1.f);
  float t = acc * lw2[c];
  #pragma unroll
  for (int off = 32; off > 0; off >>= 1) t += __shfl_xor(t, off, 64);
  if (c == 0) out[g] = t + lb2[0];
}

extern "C" void kernel_launch(void* const* d_in, const int* in_sizes, int n_in,
                              void* d_out, int out_size, void* d_ws, size_t ws_size,
                              hipStream_t stream){
  const float* x    = (const float*)d_in[0];
  const int*  ei    = (const int*) d_in[1];
  const int*  batch = (const int*) d_in[2];
  const float* W1l = (const float*)d_in[3];
  const float* b1l = (const float*)d_in[4];
  const float* W1r = (const float*)d_in[5];
  const float* b1r = (const float*)d_in[6];
  const float* att1= (const float*)d_in[7];
  const float* bias1=(const float*)d_in[8];
  const float* gamma1=(const float*)d_in[9];
  const float* beta1 =(const float*)d_in[10];
  const float* W2l = (const float*)d_in[11];
  const float* b2l = (const float*)d_in[12];
  const float* W2r = (const float*)d_in[13];
  const float* b2r = (const float*)d_in[14];
  const float* att2= (const float*)d_in[15];
  const float* bias2=(const float*)d_in[16];
  const float* gamma2=(const float*)d_in[17];
  const float* beta2 =(const float*)d_in[18];
  const float* lw1 = (const float*)d_in[19];
  const float* lb1 = (const float*)d_in[20];
  const float* lw2 = (const float*)d_in[21];
  const float* lb2 = (const float*)d_in[22];
  float* out = (float*)d_out;

  char* w = (char*)d_ws;
  size_t off = 0;
  auto take = [&](size_t bytes)->char*{
    char* p = w + off;
    off = (off + bytes + 255) & ~(size_t)255;
    return p;
  };
  int*   ro    = (int*)  take((NN+1)*sizeof(int));
  int*   cur   = (int*)  take((size_t)NN*sizeof(int));
  int*   ssrc  = (int*)  take((size_t)ET*sizeof(int));
  int*   part  = (int*)  take(64*sizeof(int));
  float* stats1= (float*)take(2*D1*sizeof(float));
  float* stats2= (float*)take(2*HD*sizeof(float));
  float* pool  = (float*)take(NG*HD*sizeof(float));
  float* pcnt  = (float*)take(NG*sizeof(float));
  float* regA  = (float*)take((size_t)NN*D1*sizeof(float));  // xl1; later xl2/xr2/h2
  float* regB  = (float*)take((size_t)NN*D1*sizeof(float));  // xr1; later h1

  float* xl1 = regA;
  float* xr1 = regB;
  float* h1  = regB;                               // overwrites xr1 (dead after k_gat1)
  float* xl2 = regA;                               // overwrites xl1 (dead after k_gat1)
  float* xr2 = regA + (size_t)NN*HD;
  float* h2  = regA + (size_t)2*NN*HD;

  // CSR build
  hipMemsetAsync(cur, 0, (size_t)NN*sizeof(int), stream);
  k_count<<<(ET+255)/256, 256, 0, stream>>>(ei, cur);
  int nsb = (NN + 1023)/1024;                       // 49 blocks
  k_scan1<<<nsb, 1024, 0, stream>>>(cur, ro, part);
  k_scan2<<<1, 64, 0, stream>>>(part, nsb);
  k_scan3<<<nsb, 1024, 0, stream>>>(part, ro);
  hipMemsetAsync(cur, 0, (size_t)NN*sizeof(int), stream);
  k_scatter<<<(ET+255)/256, 256, 0, stream>>>(ei, ro, cur, ssrc);

  // Layer 1: GEMM then fused gather+softmax+aggregate
  k_gemm1<<<(NN+3)/4, 256, 0, stream>>>(x, W1l, b1l, W1r, b1r, xl1, xr1);
  k_gat1<<<(NN+3)/4, 256, 0, stream>>>(ro, ssrc, xl1, xr1, att1, bias1, h1);
  hipMemsetAsync(stats1, 0, 2*D1*sizeof(float), stream);
  k_bnstats<<<196, 256, 0, stream>>>(h1, stats1, D1, 256);
  k_bn1<<<2048, 256, 0, stream>>>(h1, stats1, gamma1, beta1);

  // Layer 2
  k_gemm2<<<(NN+3)/4, 256, 0, stream>>>(h1, W2l, b2l, W2r, b2r, xl2, xr2);
  k_gat2<<<(NN+3)/4, 256, 0, stream>>>(ro, ssrc, xl2, xr2, att2, bias2, h2);
  hipMemsetAsync(stats2, 0, 2*HD*sizeof(float), stream);
  k_bnstats<<<196, 256, 0, stream>>>(h2, stats2, HD, 256);

  // BN2 + ELU + pool (sorted-batch strip reduction), then MLP head
  hipMemsetAsync(pool, 0, NG*HD*sizeof(float), stream);
  hipMemsetAsync(pcnt, 0, NG*sizeof(float), stream);
  {
    int waves = (NN + PW_NODES - 1)/PW_NODES;       // 250
    int blocks = (waves + 3)/4;                      // 63
    k_bn2pool<<<blocks, 256, 0, stream>>>(h2, stats2, gamma2, beta2, batch, pool, pcnt);
  }
  k_mlp<<<NG, 64, 0, stream>>>(pool, pcnt, lw1, lb1, lw2, lb2, out);
}

// Round 7
// 623.055 us; speedup vs baseline: 2.5868x; 1.3206x over previous
//
#include <hip/hip_runtime.h>
#include <hip/hip_bf16.h>

#define NN 50000
#define NE 800000
#define ET (NE + NN)          // 850000 edges incl. self-loops
#define NG 64
#define IND 128
#define HD 64
#define NH 4
#define D1 256                // NH*HD
#define BN_EPS 1e-5f
#define SLOPE 0.2f
#define PW_NODES 200          // nodes per wave in k_bn2pool

// ---------------- CSR build (by dst) ----------------
__global__ void k_count(const int* __restrict__ ei, int* __restrict__ cnt){
  int e = blockIdx.x*256 + threadIdx.x;
  if (e >= ET) return;
  int d = (e < NE) ? ei[NE + e] : (e - NE);
  atomicAdd(&cnt[d], 1);
}

__global__ __launch_bounds__(1024) void k_scan1(const int* __restrict__ cnt,
                                                int* __restrict__ ro, int* __restrict__ part){
  __shared__ int s[1024];
  int i = blockIdx.x*1024 + threadIdx.x;
  int v = (i < NN) ? cnt[i] : 0;
  s[threadIdx.x] = v;
  __syncthreads();
  for (int off = 1; off < 1024; off <<= 1){
    int t = (threadIdx.x >= off) ? s[threadIdx.x - off] : 0;
    __syncthreads();
    s[threadIdx.x] += t;
    __syncthreads();
  }
  if (i < NN) ro[i] = s[threadIdx.x] - v;        // exclusive within block
  if (threadIdx.x == 1023) part[blockIdx.x] = s[1023];
}

__global__ __launch_bounds__(64) void k_scan2(int* __restrict__ part, int nb){
  __shared__ int s[64];
  int v = (threadIdx.x < nb) ? part[threadIdx.x] : 0;
  s[threadIdx.x] = v;
  __syncthreads();
  for (int off = 1; off < 64; off <<= 1){
    int t = (threadIdx.x >= off) ? s[threadIdx.x - off] : 0;
    __syncthreads();
    s[threadIdx.x] += t;
    __syncthreads();
  }
  if (threadIdx.x < nb) part[threadIdx.x] = s[threadIdx.x] - v;  // exclusive
}

__global__ __launch_bounds__(1024) void k_scan3(const int* __restrict__ part, int* __restrict__ ro){
  int i = blockIdx.x*1024 + threadIdx.x;
  if (i < NN) ro[i] += part[blockIdx.x];
  if (i == 0) ro[NN] = ET;
}

__global__ void k_scatter(const int* __restrict__ ei, const int* __restrict__ ro,
                          int* __restrict__ cur, int* __restrict__ ssrc){
  int e = blockIdx.x*256 + threadIdx.x;
  if (e >= ET) return;
  int s, d;
  if (e < NE){ s = ei[e]; d = ei[NE + e]; } else { s = e - NE; d = s; }
  int pos = ro[d] + atomicAdd(&cur[d], 1);
  ssrc[pos] = s;
}

// ---------------- Register-tiled dual GEMM ----------------
// C = A[M,KT] @ [Wa|Wb][KT, 2*NOUT] + [ba|bb]; Ca gets cols [0,NOUT), Cb cols [NOUT,2NOUT).
// BM=64, BN=128, BK=32. 256 threads; each computes an 8x4 micro-tile.
template<int KT, int NOUT>
__global__ __launch_bounds__(256) void k_gemm(const float* __restrict__ A,
      const float* __restrict__ Wa, const float* __restrict__ ba,
      const float* __restrict__ Wb, const float* __restrict__ bb,
      float* __restrict__ Ca, float* __restrict__ Cb){
  __shared__ float sxT[32][68];   // A-tile transposed, padded (272B rows, 16B-aligned)
  __shared__ float sw[32][128];   // W-tile
  int t  = threadIdx.x;
  int tx = t & 31;                // col group: 4 cols at tx*4
  int ty = t >> 5;                // row group: 8 rows at ty*8
  int n0 = blockIdx.x*64;
  int cb0 = blockIdx.y*128;

  float acc[8][4];
  #pragma unroll
  for (int i = 0; i < 8; i++)
    #pragma unroll
    for (int j = 0; j < 4; j++) acc[i][j] = 0.f;

  int ak4 = (t & 7)*4;            // staging: k-chunk
  int ar  = t >> 3;               // staging: row 0..31
  int wc4 = (t & 31)*4;           // staging: col chunk
  int wk  = t >> 5;               // staging: k row 0..7

  for (int kb = 0; kb < KT/32; kb++){
    // stage A (transposed)
    #pragma unroll
    for (int p = 0; p < 2; p++){
      int r = ar + p*32;
      int gn = n0 + r;
      float4 v = make_float4(0.f,0.f,0.f,0.f);
      if (gn < NN) v = *reinterpret_cast<const float4*>(&A[(size_t)gn*KT + kb*32 + ak4]);
      sxT[ak4+0][r] = v.x; sxT[ak4+1][r] = v.y;
      sxT[ak4+2][r] = v.z; sxT[ak4+3][r] = v.w;
    }
    // stage W
    {
      int cn = cb0 + wc4;
      const float* wp = (cn < NOUT) ? &Wa[(size_t)(kb*32)*NOUT + cn]
                                    : &Wb[(size_t)(kb*32)*NOUT + (cn - NOUT)];
      #pragma unroll
      for (int p = 0; p < 4; p++){
        int k = wk + p*8;
        *reinterpret_cast<float4*>(&sw[k][wc4]) =
            *reinterpret_cast<const float4*>(&wp[(size_t)k*NOUT]);
      }
    }
    __syncthreads();
    #pragma unroll
    for (int k = 0; k < 32; k++){
      float4 a0 = *reinterpret_cast<const float4*>(&sxT[k][ty*8]);
      float4 a1 = *reinterpret_cast<const float4*>(&sxT[k][ty*8 + 4]);
      float4 b  = *reinterpret_cast<const float4*>(&sw[k][tx*4]);
      float av[8] = {a0.x,a0.y,a0.z,a0.w,a1.x,a1.y,a1.z,a1.w};
      #pragma unroll
      for (int i = 0; i < 8; i++){
        acc[i][0] += av[i]*b.x;
        acc[i][1] += av[i]*b.y;
        acc[i][2] += av[i]*b.z;
        acc[i][3] += av[i]*b.w;
      }
    }
    __syncthreads();
  }

  // epilogue: bias + write (each thread's 4 cols lie in one half; NOUT % 4 == 0)
  int cn = cb0 + tx*4;
  bool first = (cn < NOUT);
  int cl = first ? cn : cn - NOUT;
  const float* bp = first ? ba : bb;
  float4 b4 = *reinterpret_cast<const float4*>(&bp[cl]);
  float* Cp = first ? Ca : Cb;
  #pragma unroll
  for (int i = 0; i < 8; i++){
    int r = n0 + ty*8 + i;
    if (r < NN){
      float4 o = make_float4(acc[i][0]+b4.x, acc[i][1]+b4.y, acc[i][2]+b4.z, acc[i][3]+b4.w);
      *reinterpret_cast<float4*>(&Cp[(size_t)r*NOUT + cl]) = o;
    }
  }
}

// ---- Fused GATv2 layer 1: per-node online-softmax over incoming edges ----
// lane: h = lane>>4 (head), c4 = (lane&15)*4 (4 columns of that head)
__global__ __launch_bounds__(256) void k_gat1(const int* __restrict__ ro, const int* __restrict__ ssrc,
      const float* __restrict__ xl, const float* __restrict__ xr,
      const float* __restrict__ att, const float* __restrict__ bias,
      float* __restrict__ out){
  int widx = threadIdx.x >> 6, lane = threadIdx.x & 63;
  int n = blockIdx.x*4 + widx;
  if (n >= NN) return;
  int base = (lane >> 4)*HD + (lane & 15)*4;
  float4 xr4 = *reinterpret_cast<const float4*>(&xr[(size_t)n*D1 + base]);
  float4 at4 = *reinterpret_cast<const float4*>(&att[base]);
  float m = -1e30f, den = 0.f;
  float ax=0.f, ay=0.f, az=0.f, aw=0.f;
  int b = ro[n], e = ro[n+1];
  for (int i = b; i < e; i++){
    int s = ssrc[i];
    float4 v = *reinterpret_cast<const float4*>(&xl[(size_t)s*D1 + base]);
    float t0 = v.x + xr4.x; t0 = (t0 > 0.f) ? t0 : SLOPE*t0;
    float t1 = v.y + xr4.y; t1 = (t1 > 0.f) ? t1 : SLOPE*t1;
    float t2 = v.z + xr4.z; t2 = (t2 > 0.f) ? t2 : SLOPE*t2;
    float t3 = v.w + xr4.w; t3 = (t3 > 0.f) ? t3 : SLOPE*t3;
    float L = at4.x*t0 + at4.y*t1 + at4.z*t2 + at4.w*t3;
    L += __shfl_xor(L, 1); L += __shfl_xor(L, 2);
    L += __shfl_xor(L, 4); L += __shfl_xor(L, 8);
    float mn = fmaxf(m, L);
    float corr = __expf(m - mn);
    float p = __expf(L - mn);
    den = den*corr + p;
    ax = ax*corr + p*v.x;
    ay = ay*corr + p*v.y;
    az = az*corr + p*v.z;
    aw = aw*corr + p*v.w;
    m = mn;
  }
  float inv = 1.f/den;
  float4 b4 = *reinterpret_cast<const float4*>(&bias[base]);
  float4 o = make_float4(ax*inv + b4.x, ay*inv + b4.y, az*inv + b4.z, aw*inv + b4.w);
  *reinterpret_cast<float4*>(&out[(size_t)n*D1 + base]) = o;
}

// ---------------- BatchNorm ----------------
__global__ __launch_bounds__(256) void k_bnstats(const float* __restrict__ h, float* __restrict__ stats,
                                                 int ncols, int rpb){
  int nrl = 256/ncols;
  int c = threadIdx.x % ncols;
  int rl = threadIdx.x / ncols;
  int r0 = blockIdx.x*rpb + rl;
  int r1 = min(NN, (blockIdx.x+1)*rpb);
  float s = 0.f, s2 = 0.f;
  for (int r = r0; r < r1; r += nrl){
    float v = h[(size_t)r*ncols + c];
    s += v; s2 += v*v;
  }
  atomicAdd(&stats[c], s);
  atomicAdd(&stats[ncols + c], s2);
}

__global__ void k_bn1(float* __restrict__ h, const float* __restrict__ stats,
                      const float* __restrict__ gamma, const float* __restrict__ beta){
  const float invn = 1.f/NN;
  size_t total = (size_t)NN*D1;
  for (size_t i = (size_t)blockIdx.x*blockDim.x + threadIdx.x; i < total;
       i += (size_t)gridDim.x*blockDim.x){
    int c = (int)(i & (D1-1));
    float mu = stats[c]*invn;
    float var = stats[D1 + c]*invn - mu*mu;
    float g = gamma[c] * rsqrtf(var + BN_EPS);
    float v = (h[i] - mu)*g + beta[c];
    h[i] = (v > 0.f) ? v : (__expf(v) - 1.f);
  }
}

// ---- Fused GATv2 layer 2 (1 head): 4 lane-groups split the edge list,
// each runs online softmax on every 4th edge; merged via shfl at the end.
__global__ __launch_bounds__(256) void k_gat2(const int* __restrict__ ro, const int* __restrict__ ssrc,
      const float* __restrict__ xl, const float* __restrict__ xr,
      const float* __restrict__ att, const float* __restrict__ bias,
      float* __restrict__ out){
  int widx = threadIdx.x >> 6, lane = threadIdx.x & 63;
  int n = blockIdx.x*4 + widx;
  if (n >= NN) return;
  int g = lane >> 4, c4 = (lane & 15)*4;
  float4 xr4 = *reinterpret_cast<const float4*>(&xr[(size_t)n*HD + c4]);
  float4 at4 = *reinterpret_cast<const float4*>(&att[c4]);
  float m = -1e30f, den = 0.f;
  float ax=0.f, ay=0.f, az=0.f, aw=0.f;
  int b = ro[n], e = ro[n+1];
  for (int i = b + g; i < e; i += 4){
    int s = ssrc[i];
    float4 v = *reinterpret_cast<const float4*>(&xl[(size_t)s*HD + c4]);
    float t0 = v.x + xr4.x; t0 = (t0 > 0.f) ? t0 : SLOPE*t0;
    float t1 = v.y + xr4.y; t1 = (t1 > 0.f) ? t1 : SLOPE*t1;
    float t2 = v.z + xr4.z; t2 = (t2 > 0.f) ? t2 : SLOPE*t2;
    float t3 = v.w + xr4.w; t3 = (t3 > 0.f) ? t3 : SLOPE*t3;
    float L = at4.x*t0 + at4.y*t1 + at4.z*t2 + at4.w*t3;
    L += __shfl_xor(L, 1); L += __shfl_xor(L, 2);
    L += __shfl_xor(L, 4); L += __shfl_xor(L, 8);
    float mn = fmaxf(m, L);
    float corr = __expf(m - mn);
    float p = __expf(L - mn);
    den = den*corr + p;
    ax = ax*corr + p*v.x;
    ay = ay*corr + p*v.y;
    az = az*corr + p*v.z;
    aw = aw*corr + p*v.w;
    m = mn;
  }
  // merge the 4 per-group partials (lanes l and l^16 / l^32 share c4)
  #pragma unroll
  for (int off = 16; off <= 32; off <<= 1){
    float mo  = __shfl_xor(m, off);
    float dno = __shfl_xor(den, off);
    float bx  = __shfl_xor(ax, off);
    float by  = __shfl_xor(ay, off);
    float bz  = __shfl_xor(az, off);
    float bw  = __shfl_xor(aw, off);
    float mn = fmaxf(m, mo);
    float c1 = __expf(m - mn), c2 = __expf(mo - mn);
    den = den*c1 + dno*c2;
    ax = ax*c1 + bx*c2;
    ay = ay*c1 + by*c2;
    az = az*c1 + bz*c2;
    aw = aw*c1 + bw*c2;
    m = mn;
  }
  float inv = 1.f/den;
  float4 b4 = *reinterpret_cast<const float4*>(&bias[c4]);
  float4 o = make_float4(ax*inv + b4.x, ay*inv + b4.y, az*inv + b4.z, aw*inv + b4.w);
  *reinterpret_cast<float4*>(&out[(size_t)n*HD + c4]) = o;
}

// BN2 + ELU + pooled sums, sorted-batch aware: one wave owns a contiguous
// node strip; per-group register accumulation, flush on group change.
__global__ __launch_bounds__(256) void k_bn2pool(const float* __restrict__ h2, const float* __restrict__ stats,
      const float* __restrict__ gamma, const float* __restrict__ beta,
      const int* __restrict__ batch, float* __restrict__ pool, float* __restrict__ pcnt){
  int wave = blockIdx.x*4 + (threadIdx.x >> 6);
  int lane = threadIdx.x & 63;
  int n0 = wave*PW_NODES;
  if (n0 >= NN) return;
  int n1 = min(NN, n0 + PW_NODES);
  const float invn = 1.f/NN;
  float mu = stats[lane]*invn;
  float var = stats[HD + lane]*invn - mu*mu;
  float sc = gamma[lane]*rsqrtf(var + BN_EPS);
  float sh = beta[lane] - mu*sc;
  int curg = batch[n0];
  float acc = 0.f, cnt = 0.f;
  for (int n = n0; n < n1; n++){
    int g = batch[n];
    if (g != curg){
      atomicAdd(&pool[curg*HD + lane], acc);
      if (lane == 0) atomicAdd(&pcnt[curg], cnt);
      acc = 0.f; cnt = 0.f; curg = g;
    }
    float v = h2[(size_t)n*HD + lane]*sc + sh;
    v = (v > 0.f) ? v : (__expf(v) - 1.f);
    acc += v; cnt += 1.f;
  }
  atomicAdd(&pool[curg*HD + lane], acc);
  if (lane == 0) atomicAdd(&pcnt[curg], cnt);
}

// final MLP: out[g] = elu(pooled@lw1+lb1) @ lw2 + lb2   (f32 output)
__global__ __launch_bounds__(64) void k_mlp(const float* __restrict__ pool, const float* __restrict__ pcnt,
      const float* __restrict__ lw1, const float* __restrict__ lb1,
      const float* __restrict__ lw2, const float* __restrict__ lb2, float* __restrict__ out){
  __shared__ float p[HD];
  int g = blockIdx.x, c = threadIdx.x;
  float cnt = fmaxf(pcnt[g], 1.f);
  p[c] = pool[g*HD + c]/cnt;
  __syncthreads();
  float acc = lb1[c];
  for (int k = 0; k < HD; k++) acc += p[k]*lw1[k*HD + c];
  acc = (acc > 0.f) ? acc : (__expf(acc) - 1.f);
  float t = acc * lw2[c];
  #pragma unroll
  for (int off = 32; off > 0; off >>= 1) t += __shfl_xor(t, off, 64);
  if (c == 0) out[g] = t + lb2[0];
}

extern "C" void kernel_launch(void* const* d_in, const int* in_sizes, int n_in,
                              void* d_out, int out_size, void* d_ws, size_t ws_size,
                              hipStream_t stream){
  const float* x    = (const float*)d_in[0];
  const int*  ei    = (const int*) d_in[1];
  const int*  batch = (const int*) d_in[2];
  const float* W1l = (const float*)d_in[3];
  const float* b1l = (const float*)d_in[4];
  const float* W1r = (const float*)d_in[5];
  const float* b1r = (const float*)d_in[6];
  const float* att1= (const float*)d_in[7];
  const float* bias1=(const float*)d_in[8];
  const float* gamma1=(const float*)d_in[9];
  const float* beta1 =(const float*)d_in[10];
  const float* W2l = (const float*)d_in[11];
  const float* b2l = (const float*)d_in[12];
  const float* W2r = (const float*)d_in[13];
  const float* b2r = (const float*)d_in[14];
  const float* att2= (const float*)d_in[15];
  const float* bias2=(const float*)d_in[16];
  const float* gamma2=(const float*)d_in[17];
  const float* beta2 =(const float*)d_in[18];
  const float* lw1 = (const float*)d_in[19];
  const float* lb1 = (const float*)d_in[20];
  const float* lw2 = (const float*)d_in[21];
  const float* lb2 = (const float*)d_in[22];
  float* out = (float*)d_out;

  char* w = (char*)d_ws;
  size_t off = 0;
  auto take = [&](size_t bytes)->char*{
    char* p = w + off;
    off = (off + bytes + 255) & ~(size_t)255;
    return p;
  };
  int*   ro    = (int*)  take((NN+1)*sizeof(int));
  int*   cur   = (int*)  take((size_t)NN*sizeof(int));
  int*   ssrc  = (int*)  take((size_t)ET*sizeof(int));
  int*   part  = (int*)  take(64*sizeof(int));
  float* stats1= (float*)take(2*D1*sizeof(float));
  float* stats2= (float*)take(2*HD*sizeof(float));
  float* pool  = (float*)take(NG*HD*sizeof(float));
  float* pcnt  = (float*)take(NG*sizeof(float));
  float* regA  = (float*)take((size_t)NN*D1*sizeof(float));  // xl1; later xl2/xr2/h2
  float* regB  = (float*)take((size_t)NN*D1*sizeof(float));  // xr1; later h1

  float* xl1 = regA;
  float* xr1 = regB;
  float* h1  = regB;                               // overwrites xr1 (dead after k_gat1)
  float* xl2 = regA;                               // overwrites xl1 (dead after k_gat1)
  float* xr2 = regA + (size_t)NN*HD;
  float* h2  = regA + (size_t)2*NN*HD;

  // CSR build
  hipMemsetAsync(cur, 0, (size_t)NN*sizeof(int), stream);
  k_count<<<(ET+255)/256, 256, 0, stream>>>(ei, cur);
  int nsb = (NN + 1023)/1024;                       // 49 blocks
  k_scan1<<<nsb, 1024, 0, stream>>>(cur, ro, part);
  k_scan2<<<1, 64, 0, stream>>>(part, nsb);
  k_scan3<<<nsb, 1024, 0, stream>>>(part, ro);
  hipMemsetAsync(cur, 0, (size_t)NN*sizeof(int), stream);
  k_scatter<<<(ET+255)/256, 256, 0, stream>>>(ei, ro, cur, ssrc);

  const int MB = (NN + 63)/64;                      // 782 row tiles

  // Layer 1: tiled dual GEMM then fused gather+softmax+aggregate
  k_gemm<IND, D1><<<dim3(MB, 4), 256, 0, stream>>>(x, W1l, b1l, W1r, b1r, xl1, xr1);
  k_gat1<<<(NN+3)/4, 256, 0, stream>>>(ro, ssrc, xl1, xr1, att1, bias1, h1);
  hipMemsetAsync(stats1, 0, 2*D1*sizeof(float), stream);
  k_bnstats<<<196, 256, 0, stream>>>(h1, stats1, D1, 256);
  k_bn1<<<2048, 256, 0, stream>>>(h1, stats1, gamma1, beta1);

  // Layer 2
  k_gemm<D1, HD><<<dim3(MB, 1), 256, 0, stream>>>(h1, W2l, b2l, W2r, b2r, xl2, xr2);
  k_gat2<<<(NN+3)/4, 256, 0, stream>>>(ro, ssrc, xl2, xr2, att2, bias2, h2);
  hipMemsetAsync(stats2, 0, 2*HD*sizeof(float), stream);
  k_bnstats<<<196, 256, 0, stream>>>(h2, stats2, HD, 256);

  // BN2 + ELU + pool (sorted-batch strip reduction), then MLP head
  hipMemsetAsync(pool, 0, NG*HD*sizeof(float), stream);
  hipMemsetAsync(pcnt, 0, NG*sizeof(float), stream);
  {
    int waves = (NN + PW_NODES - 1)/PW_NODES;       // 250
    int blocks = (waves + 3)/4;                      // 63
    k_bn2pool<<<blocks, 256, 0, stream>>>(h2, stats2, gamma2, beta2, batch, pool, pcnt);
  }
  k_mlp<<<NG, 64, 0, stream>>>(pool, pcnt, lw1, lb1, lw2, lb2, out);
}

// Round 8
// 600.163 us; speedup vs baseline: 2.6854x; 1.0381x over previous
//
#include <hip/hip_runtime.h>
#include <hip/hip_bf16.h>

#define NN 50000
#define NE 800000
#define ET (NE + NN)          // 850000 edges incl. self-loops
#define NG 64
#define IND 128
#define HD 64
#define NH 4
#define D1 256                // NH*HD
#define BN_EPS 1e-5f
#define SLOPE 0.2f
#define PW_NODES 200          // nodes per wave in k_bn2pool

typedef unsigned short u16;

__device__ __forceinline__ float b2f(u16 u){
  union { unsigned int i; float f; } c; c.i = ((unsigned int)u) << 16; return c.f;
}
__device__ __forceinline__ u16 f2b(float f){
  unsigned int u = __float_as_uint(f);
  u = (u + 0x7FFF + ((u >> 16) & 1)) >> 16;   // round-to-nearest-even
  return (u16)u;
}

// ---------------- CSR build (by dst) ----------------
__global__ void k_count(const int* __restrict__ ei, int* __restrict__ cnt){
  int e = blockIdx.x*256 + threadIdx.x;
  if (e >= ET) return;
  int d = (e < NE) ? ei[NE + e] : (e - NE);
  atomicAdd(&cnt[d], 1);
}

__global__ __launch_bounds__(1024) void k_scan1(const int* __restrict__ cnt,
                                                int* __restrict__ ro, int* __restrict__ part){
  __shared__ int s[1024];
  int i = blockIdx.x*1024 + threadIdx.x;
  int v = (i < NN) ? cnt[i] : 0;
  s[threadIdx.x] = v;
  __syncthreads();
  for (int off = 1; off < 1024; off <<= 1){
    int t = (threadIdx.x >= off) ? s[threadIdx.x - off] : 0;
    __syncthreads();
    s[threadIdx.x] += t;
    __syncthreads();
  }
  if (i < NN) ro[i] = s[threadIdx.x] - v;        // exclusive within block
  if (threadIdx.x == 1023) part[blockIdx.x] = s[1023];
}

__global__ __launch_bounds__(64) void k_scan2(int* __restrict__ part, int nb){
  __shared__ int s[64];
  int v = (threadIdx.x < nb) ? part[threadIdx.x] : 0;
  s[threadIdx.x] = v;
  __syncthreads();
  for (int off = 1; off < 64; off <<= 1){
    int t = (threadIdx.x >= off) ? s[threadIdx.x - off] : 0;
    __syncthreads();
    s[threadIdx.x] += t;
    __syncthreads();
  }
  if (threadIdx.x < nb) part[threadIdx.x] = s[threadIdx.x] - v;  // exclusive
}

__global__ __launch_bounds__(1024) void k_scan3(const int* __restrict__ part, int* __restrict__ ro){
  int i = blockIdx.x*1024 + threadIdx.x;
  if (i < NN) ro[i] += part[blockIdx.x];
  if (i == 0) ro[NN] = ET;
}

__global__ void k_scatter(const int* __restrict__ ei, const int* __restrict__ ro,
                          int* __restrict__ cur, int* __restrict__ ssrc){
  int e = blockIdx.x*256 + threadIdx.x;
  if (e >= ET) return;
  int s, d;
  if (e < NE){ s = ei[e]; d = ei[NE + e]; } else { s = e - NE; d = s; }
  int pos = ro[d] + atomicAdd(&cur[d], 1);
  ssrc[pos] = s;
}

// ---------------- Register-tiled dual GEMM (bf16 output) ----------------
// C = A[M,KT] @ [Wa|Wb][KT, 2*NOUT] + [ba|bb]; Ca gets cols [0,NOUT), Cb cols [NOUT,2NOUT).
// BM=64, BN=128, BK=32. 256 threads; each computes an 8x4 micro-tile.
template<int KT, int NOUT>
__global__ __launch_bounds__(256) void k_gemm(const float* __restrict__ A,
      const float* __restrict__ Wa, const float* __restrict__ ba,
      const float* __restrict__ Wb, const float* __restrict__ bb,
      u16* __restrict__ Ca, u16* __restrict__ Cb){
  __shared__ float sxT[32][68];   // A-tile transposed, padded
  __shared__ float sw[32][128];   // W-tile
  int t  = threadIdx.x;
  int tx = t & 31;                // col group: 4 cols at tx*4
  int ty = t >> 5;                // row group: 8 rows at ty*8
  int n0 = blockIdx.x*64;
  int cb0 = blockIdx.y*128;

  float acc[8][4];
  #pragma unroll
  for (int i = 0; i < 8; i++)
    #pragma unroll
    for (int j = 0; j < 4; j++) acc[i][j] = 0.f;

  int ak4 = (t & 7)*4;            // staging: k-chunk
  int ar  = t >> 3;               // staging: row 0..31
  int wc4 = (t & 31)*4;           // staging: col chunk
  int wk  = t >> 5;               // staging: k row 0..7

  for (int kb = 0; kb < KT/32; kb++){
    #pragma unroll
    for (int p = 0; p < 2; p++){
      int r = ar + p*32;
      int gn = n0 + r;
      float4 v = make_float4(0.f,0.f,0.f,0.f);
      if (gn < NN) v = *reinterpret_cast<const float4*>(&A[(size_t)gn*KT + kb*32 + ak4]);
      sxT[ak4+0][r] = v.x; sxT[ak4+1][r] = v.y;
      sxT[ak4+2][r] = v.z; sxT[ak4+3][r] = v.w;
    }
    {
      int cn = cb0 + wc4;
      const float* wp = (cn < NOUT) ? &Wa[(size_t)(kb*32)*NOUT + cn]
                                    : &Wb[(size_t)(kb*32)*NOUT + (cn - NOUT)];
      #pragma unroll
      for (int p = 0; p < 4; p++){
        int k = wk + p*8;
        *reinterpret_cast<float4*>(&sw[k][wc4]) =
            *reinterpret_cast<const float4*>(&wp[(size_t)k*NOUT]);
      }
    }
    __syncthreads();
    #pragma unroll
    for (int k = 0; k < 32; k++){
      float4 a0 = *reinterpret_cast<const float4*>(&sxT[k][ty*8]);
      float4 a1 = *reinterpret_cast<const float4*>(&sxT[k][ty*8 + 4]);
      float4 b  = *reinterpret_cast<const float4*>(&sw[k][tx*4]);
      float av[8] = {a0.x,a0.y,a0.z,a0.w,a1.x,a1.y,a1.z,a1.w};
      #pragma unroll
      for (int i = 0; i < 8; i++){
        acc[i][0] += av[i]*b.x;
        acc[i][1] += av[i]*b.y;
        acc[i][2] += av[i]*b.z;
        acc[i][3] += av[i]*b.w;
      }
    }
    __syncthreads();
  }

  // epilogue: bias + bf16 pack + write (each thread's 4 cols lie in one half)
  int cn = cb0 + tx*4;
  bool first = (cn < NOUT);
  int cl = first ? cn : cn - NOUT;
  const float* bp = first ? ba : bb;
  float4 b4 = *reinterpret_cast<const float4*>(&bp[cl]);
  u16* Cp = first ? Ca : Cb;
  #pragma unroll
  for (int i = 0; i < 8; i++){
    int r = n0 + ty*8 + i;
    if (r < NN){
      ushort4 o;
      o.x = f2b(acc[i][0]+b4.x); o.y = f2b(acc[i][1]+b4.y);
      o.z = f2b(acc[i][2]+b4.z); o.w = f2b(acc[i][3]+b4.w);
      *reinterpret_cast<ushort4*>(&Cp[(size_t)r*NOUT + cl]) = o;
    }
  }
}

// ---- Fused GATv2 layer 1 (bf16 xl/xr): per-node online-softmax ----
// lane: h = lane>>4 (head), c4 = (lane&15)*4 (4 columns of that head)
__global__ __launch_bounds__(256) void k_gat1(const int* __restrict__ ro, const int* __restrict__ ssrc,
      const u16* __restrict__ xl, const u16* __restrict__ xr,
      const float* __restrict__ att, const float* __restrict__ bias,
      float* __restrict__ out){
  int widx = threadIdx.x >> 6, lane = threadIdx.x & 63;
  int n = blockIdx.x*4 + widx;
  if (n >= NN) return;
  int base = (lane >> 4)*HD + (lane & 15)*4;
  ushort4 ur = *reinterpret_cast<const ushort4*>(&xr[(size_t)n*D1 + base]);
  float xr0 = b2f(ur.x), xr1 = b2f(ur.y), xr2 = b2f(ur.z), xr3 = b2f(ur.w);
  float4 at4 = *reinterpret_cast<const float4*>(&att[base]);
  float m = -1e30f, den = 0.f;
  float ax=0.f, ay=0.f, az=0.f, aw=0.f;
  int b = ro[n], e = ro[n+1];
  for (int i = b; i < e; i++){
    int s = ssrc[i];
    ushort4 u = *reinterpret_cast<const ushort4*>(&xl[(size_t)s*D1 + base]);
    float vx = b2f(u.x), vy = b2f(u.y), vz = b2f(u.z), vw = b2f(u.w);
    float t0 = vx + xr0; t0 = (t0 > 0.f) ? t0 : SLOPE*t0;
    float t1 = vy + xr1; t1 = (t1 > 0.f) ? t1 : SLOPE*t1;
    float t2 = vz + xr2; t2 = (t2 > 0.f) ? t2 : SLOPE*t2;
    float t3 = vw + xr3; t3 = (t3 > 0.f) ? t3 : SLOPE*t3;
    float L = at4.x*t0 + at4.y*t1 + at4.z*t2 + at4.w*t3;
    L += __shfl_xor(L, 1); L += __shfl_xor(L, 2);
    L += __shfl_xor(L, 4); L += __shfl_xor(L, 8);
    float mn = fmaxf(m, L);
    float corr = __expf(m - mn);
    float p = __expf(L - mn);
    den = den*corr + p;
    ax = ax*corr + p*vx;
    ay = ay*corr + p*vy;
    az = az*corr + p*vz;
    aw = aw*corr + p*vw;
    m = mn;
  }
  float inv = 1.f/den;
  float4 b4 = *reinterpret_cast<const float4*>(&bias[base]);
  float4 o = make_float4(ax*inv + b4.x, ay*inv + b4.y, az*inv + b4.z, aw*inv + b4.w);
  *reinterpret_cast<float4*>(&out[(size_t)n*D1 + base]) = o;
}

// ---------------- BatchNorm ----------------
__global__ __launch_bounds__(256) void k_bnstats(const float* __restrict__ h, float* __restrict__ stats,
                                                 int ncols, int rpb){
  int nrl = 256/ncols;
  int c = threadIdx.x % ncols;
  int rl = threadIdx.x / ncols;
  int r0 = blockIdx.x*rpb + rl;
  int r1 = min(NN, (blockIdx.x+1)*rpb);
  float s = 0.f, s2 = 0.f;
  for (int r = r0; r < r1; r += nrl){
    float v = h[(size_t)r*ncols + c];
    s += v; s2 += v*v;
  }
  atomicAdd(&stats[c], s);
  atomicAdd(&stats[ncols + c], s2);
}

__global__ void k_bn1(float* __restrict__ h, const float* __restrict__ stats,
                      const float* __restrict__ gamma, const float* __restrict__ beta){
  const float invn = 1.f/NN;
  size_t total = (size_t)NN*D1;
  for (size_t i = (size_t)blockIdx.x*blockDim.x + threadIdx.x; i < total;
       i += (size_t)gridDim.x*blockDim.x){
    int c = (int)(i & (D1-1));
    float mu = stats[c]*invn;
    float var = stats[D1 + c]*invn - mu*mu;
    float g = gamma[c] * rsqrtf(var + BN_EPS);
    float v = (h[i] - mu)*g + beta[c];
    h[i] = (v > 0.f) ? v : (__expf(v) - 1.f);
  }
}

// ---- Fused GATv2 layer 2 (1 head, bf16 xl/xr): 4 lane-groups split edges ----
__global__ __launch_bounds__(256) void k_gat2(const int* __restrict__ ro, const int* __restrict__ ssrc,
      const u16* __restrict__ xl, const u16* __restrict__ xr,
      const float* __restrict__ att, const float* __restrict__ bias,
      float* __restrict__ out){
  int widx = threadIdx.x >> 6, lane = threadIdx.x & 63;
  int n = blockIdx.x*4 + widx;
  if (n >= NN) return;
  int g = lane >> 4, c4 = (lane & 15)*4;
  ushort4 ur = *reinterpret_cast<const ushort4*>(&xr[(size_t)n*HD + c4]);
  float xr0 = b2f(ur.x), xr1 = b2f(ur.y), xr2 = b2f(ur.z), xr3 = b2f(ur.w);
  float4 at4 = *reinterpret_cast<const float4*>(&att[c4]);
  float m = -1e30f, den = 0.f;
  float ax=0.f, ay=0.f, az=0.f, aw=0.f;
  int b = ro[n], e = ro[n+1];
  for (int i = b + g; i < e; i += 4){
    int s = ssrc[i];
    ushort4 u = *reinterpret_cast<const ushort4*>(&xl[(size_t)s*HD + c4]);
    float vx = b2f(u.x), vy = b2f(u.y), vz = b2f(u.z), vw = b2f(u.w);
    float t0 = vx + xr0; t0 = (t0 > 0.f) ? t0 : SLOPE*t0;
    float t1 = vy + xr1; t1 = (t1 > 0.f) ? t1 : SLOPE*t1;
    float t2 = vz + xr2; t2 = (t2 > 0.f) ? t2 : SLOPE*t2;
    float t3 = vw + xr3; t3 = (t3 > 0.f) ? t3 : SLOPE*t3;
    float L = at4.x*t0 + at4.y*t1 + at4.z*t2 + at4.w*t3;
    L += __shfl_xor(L, 1); L += __shfl_xor(L, 2);
    L += __shfl_xor(L, 4); L += __shfl_xor(L, 8);
    float mn = fmaxf(m, L);
    float corr = __expf(m - mn);
    float p = __expf(L - mn);
    den = den*corr + p;
    ax = ax*corr + p*vx;
    ay = ay*corr + p*vy;
    az = az*corr + p*vz;
    aw = aw*corr + p*vw;
    m = mn;
  }
  // merge the 4 per-group partials (lanes l^16 / l^32 share c4)
  #pragma unroll
  for (int off = 16; off <= 32; off <<= 1){
    float mo  = __shfl_xor(m, off);
    float dno = __shfl_xor(den, off);
    float bx  = __shfl_xor(ax, off);
    float by  = __shfl_xor(ay, off);
    float bz  = __shfl_xor(az, off);
    float bw  = __shfl_xor(aw, off);
    float mn = fmaxf(m, mo);
    float c1 = __expf(m - mn), c2 = __expf(mo - mn);
    den = den*c1 + dno*c2;
    ax = ax*c1 + bx*c2;
    ay = ay*c1 + by*c2;
    az = az*c1 + bz*c2;
    aw = aw*c1 + bw*c2;
    m = mn;
  }
  float inv = 1.f/den;
  float4 b4 = *reinterpret_cast<const float4*>(&bias[c4]);
  float4 o = make_float4(ax*inv + b4.x, ay*inv + b4.y, az*inv + b4.z, aw*inv + b4.w);
  *reinterpret_cast<float4*>(&out[(size_t)n*HD + c4]) = o;
}

// BN2 + ELU + pooled sums, sorted-batch strip reduction
__global__ __launch_bounds__(256) void k_bn2pool(const float* __restrict__ h2, const float* __restrict__ stats,
      const float* __restrict__ gamma, const float* __restrict__ beta,
      const int* __restrict__ batch, float* __restrict__ pool, float* __restrict__ pcnt){
  int wave = blockIdx.x*4 + (threadIdx.x >> 6);
  int lane = threadIdx.x & 63;
  int n0 = wave*PW_NODES;
  if (n0 >= NN) return;
  int n1 = min(NN, n0 + PW_NODES);
  const float invn = 1.f/NN;
  float mu = stats[lane]*invn;
  float var = stats[HD + lane]*invn - mu*mu;
  float sc = gamma[lane]*rsqrtf(var + BN_EPS);
  float sh = beta[lane] - mu*sc;
  int curg = batch[n0];
  float acc = 0.f, cnt = 0.f;
  for (int n = n0; n < n1; n++){
    int g = batch[n];
    if (g != curg){
      atomicAdd(&pool[curg*HD + lane], acc);
      if (lane == 0) atomicAdd(&pcnt[curg], cnt);
      acc = 0.f; cnt = 0.f; curg = g;
    }
    float v = h2[(size_t)n*HD + lane]*sc + sh;
    v = (v > 0.f) ? v : (__expf(v) - 1.f);
    acc += v; cnt += 1.f;
  }
  atomicAdd(&pool[curg*HD + lane], acc);
  if (lane == 0) atomicAdd(&pcnt[curg], cnt);
}

// final MLP: out[g] = elu(pooled@lw1+lb1) @ lw2 + lb2   (f32 output)
__global__ __launch_bounds__(64) void k_mlp(const float* __restrict__ pool, const float* __restrict__ pcnt,
      const float* __restrict__ lw1, const float* __restrict__ lb1,
      const float* __restrict__ lw2, const float* __restrict__ lb2, float* __restrict__ out){
  __shared__ float p[HD];
  int g = blockIdx.x, c = threadIdx.x;
  float cnt = fmaxf(pcnt[g], 1.f);
  p[c] = pool[g*HD + c]/cnt;
  __syncthreads();
  float acc = lb1[c];
  for (int k = 0; k < HD; k++) acc += p[k]*lw1[k*HD + c];
  acc = (acc > 0.f) ? acc : (__expf(acc) - 1.f);
  float t = acc * lw2[c];
  #pragma unroll
  for (int off = 32; off > 0; off >>= 1) t += __shfl_xor(t, off, 64);
  if (c == 0) out[g] = t + lb2[0];
}

extern "C" void kernel_launch(void* const* d_in, const int* in_sizes, int n_in,
                              void* d_out, int out_size, void* d_ws, size_t ws_size,
                              hipStream_t stream){
  const float* x    = (const float*)d_in[0];
  const int*  ei    = (const int*) d_in[1];
  const int*  batch = (const int*) d_in[2];
  const float* W1l = (const float*)d_in[3];
  const float* b1l = (const float*)d_in[4];
  const float* W1r = (const float*)d_in[5];
  const float* b1r = (const float*)d_in[6];
  const float* att1= (const float*)d_in[7];
  const float* bias1=(const float*)d_in[8];
  const float* gamma1=(const float*)d_in[9];
  const float* beta1 =(const float*)d_in[10];
  const float* W2l = (const float*)d_in[11];
  const float* b2l = (const float*)d_in[12];
  const float* W2r = (const float*)d_in[13];
  const float* b2r = (const float*)d_in[14];
  const float* att2= (const float*)d_in[15];
  const float* bias2=(const float*)d_in[16];
  const float* gamma2=(const float*)d_in[17];
  const float* beta2 =(const float*)d_in[18];
  const float* lw1 = (const float*)d_in[19];
  const float* lb1 = (const float*)d_in[20];
  const float* lw2 = (const float*)d_in[21];
  const float* lb2 = (const float*)d_in[22];
  float* out = (float*)d_out;

  char* w = (char*)d_ws;
  size_t off = 0;
  auto take = [&](size_t bytes)->char*{
    char* p = w + off;
    off = (off + bytes + 255) & ~(size_t)255;
    return p;
  };
  int*   ro    = (int*)  take((NN+1)*sizeof(int));
  int*   cur   = (int*)  take((size_t)NN*sizeof(int));
  int*   ssrc  = (int*)  take((size_t)ET*sizeof(int));
  int*   part  = (int*)  take(64*sizeof(int));
  float* stats1= (float*)take(2*D1*sizeof(float));
  float* stats2= (float*)take(2*HD*sizeof(float));
  float* pool  = (float*)take(NG*HD*sizeof(float));
  float* pcnt  = (float*)take(NG*sizeof(float));
  char*  bufA  = take((size_t)NN*D1*2*sizeof(u16));   // xlb1+xrb1; later xlb2+xrb2+h2
  float* h1    = (float*)take((size_t)NN*D1*sizeof(float));

  u16* xlb1 = (u16*)bufA;
  u16* xrb1 = xlb1 + (size_t)NN*D1;
  u16* xlb2 = (u16*)bufA;                             // overlays dead xlb1
  u16* xrb2 = xlb2 + (size_t)NN*HD;
  float* h2 = (float*)(bufA + (size_t)2*NN*HD*sizeof(u16));

  // CSR build
  hipMemsetAsync(cur, 0, (size_t)NN*sizeof(int), stream);
  k_count<<<(ET+255)/256, 256, 0, stream>>>(ei, cur);
  int nsb = (NN + 1023)/1024;                       // 49 blocks
  k_scan1<<<nsb, 1024, 0, stream>>>(cur, ro, part);
  k_scan2<<<1, 64, 0, stream>>>(part, nsb);
  k_scan3<<<nsb, 1024, 0, stream>>>(part, ro);
  hipMemsetAsync(cur, 0, (size_t)NN*sizeof(int), stream);
  k_scatter<<<(ET+255)/256, 256, 0, stream>>>(ei, ro, cur, ssrc);

  const int MB = (NN + 63)/64;                      // 782 row tiles

  // Layer 1: tiled dual GEMM (bf16 out) then fused gather+softmax+aggregate
  k_gemm<IND, D1><<<dim3(MB, 4), 256, 0, stream>>>(x, W1l, b1l, W1r, b1r, xlb1, xrb1);
  k_gat1<<<(NN+3)/4, 256, 0, stream>>>(ro, ssrc, xlb1, xrb1, att1, bias1, h1);
  hipMemsetAsync(stats1, 0, 2*D1*sizeof(float), stream);
  k_bnstats<<<196, 256, 0, stream>>>(h1, stats1, D1, 256);
  k_bn1<<<2048, 256, 0, stream>>>(h1, stats1, gamma1, beta1);

  // Layer 2
  k_gemm<D1, HD><<<dim3(MB, 1), 256, 0, stream>>>(h1, W2l, b2l, W2r, b2r, xlb2, xrb2);
  k_gat2<<<(NN+3)/4, 256, 0, stream>>>(ro, ssrc, xlb2, xrb2, att2, bias2, h2);
  hipMemsetAsync(stats2, 0, 2*HD*sizeof(float), stream);
  k_bnstats<<<196, 256, 0, stream>>>(h2, stats2, HD, 256);

  // BN2 + ELU + pool (sorted-batch strip reduction), then MLP head
  hipMemsetAsync(pool, 0, NG*HD*sizeof(float), stream);
  hipMemsetAsync(pcnt, 0, NG*sizeof(float), stream);
  {
    int waves = (NN + PW_NODES - 1)/PW_NODES;       // 250
    int blocks = (waves + 3)/4;                      // 63
    k_bn2pool<<<blocks, 256, 0, stream>>>(h2, stats2, gamma2, beta2, batch, pool, pcnt);
  }
  k_mlp<<<NG, 64, 0, stream>>>(pool, pcnt, lw1, lb1, lw2, lb2, out);
}